// Round 1
// baseline (4489.521 us; speedup 1.0000x reference)
//
#include <hip/hip_runtime.h>
#include <math.h>

#define DIMC   3072
#define NH     24
#define HD     128
#define QKV_N  9216
#define S_TXT  256
#define S_IMG  2048
#define S_TOT  2304

// ---------------------------------------------------------------------------
// QKV GEMM: C[2304][9216] = concat(enc,hid) @ Wqkv + bqkv   (fp32)
// 64x64 tile, BK=16, 256 threads, 4x4 micro-tile per thread.
// ---------------------------------------------------------------------------
__global__ __launch_bounds__(256) void qkv_gemm(
    const float* __restrict__ enc, const float* __restrict__ hid,
    const float* __restrict__ W, const float* __restrict__ bias,
    float* __restrict__ C)
{
    const int K = DIMC, N = QKV_N;
    __shared__ float As[16][68];   // [k][m], pad 4 keeps float4 alignment
    __shared__ float Bs[16][68];   // [k][n]
    const int bm = blockIdx.y * 64;
    const int bn = blockIdx.x * 64;
    const int tid = threadIdx.x;
    const int tx = tid & 15, ty = tid >> 4;

    // A loader: thread -> row ra (0..63), k-chunk ca (0,4,8,12)
    const int ra = tid >> 2;
    const int ca = (tid & 3) * 4;
    const int grow = bm + ra;
    const float* Arow = (grow < S_TXT) ? (enc + (size_t)grow * DIMC)
                                       : (hid + (size_t)(grow - S_TXT) * DIMC);
    // B loader: thread -> k-row rb (0..15), col cb (0..60 step 4)
    const int rb = tid >> 4;
    const int cb = (tid & 15) * 4;

    float acc[4][4] = {};

    for (int k0 = 0; k0 < K; k0 += 16) {
        float4 av = *(const float4*)(Arow + k0 + ca);
        float4 bv = *(const float4*)(W + (size_t)(k0 + rb) * N + bn + cb);
        As[ca + 0][ra] = av.x;
        As[ca + 1][ra] = av.y;
        As[ca + 2][ra] = av.z;
        As[ca + 3][ra] = av.w;
        *(float4*)&Bs[rb][cb] = bv;
        __syncthreads();
#pragma unroll
        for (int kk = 0; kk < 16; ++kk) {
            float4 a = *(const float4*)&As[kk][ty * 4];
            float4 b = *(const float4*)&Bs[kk][tx * 4];
            float aa[4] = {a.x, a.y, a.z, a.w};
            float bb[4] = {b.x, b.y, b.z, b.w};
#pragma unroll
            for (int i = 0; i < 4; ++i)
#pragma unroll
                for (int j = 0; j < 4; ++j)
                    acc[i][j] += aa[i] * bb[j];
        }
        __syncthreads();
    }

#pragma unroll
    for (int i = 0; i < 4; ++i) {
        const int r = bm + ty * 4 + i;
        float4 o;
        o.x = acc[i][0] + bias[bn + tx * 4 + 0];
        o.y = acc[i][1] + bias[bn + tx * 4 + 1];
        o.z = acc[i][2] + bias[bn + tx * 4 + 2];
        o.w = acc[i][3] + bias[bn + tx * 4 + 3];
        *(float4*)(C + (size_t)r * N + bn + tx * 4) = o;
    }
}

// ---------------------------------------------------------------------------
// Per-head LayerNorm on q and k, then interleaved RoPE on image rows (s>=256).
// One wave (64 lanes) per (s, q/k, head) row of 128 elements; 4 waves/block.
// ---------------------------------------------------------------------------
__global__ __launch_bounds__(256) void ln_rope(
    float* __restrict__ qkv,
    const float* __restrict__ cost, const float* __restrict__ sint)
{
    const int wave = threadIdx.x >> 6;
    const int lane = threadIdx.x & 63;
    const int task = blockIdx.x * 4 + wave;     // < 2304*2*24 = 110592
    const int s   = task / 48;
    const int rem = task % 48;
    const int qk  = rem / 24;                   // 0 = q, 1 = k
    const int h   = rem % 24;

    float* p = qkv + (size_t)s * QKV_N + qk * DIMC + h * HD;
    float2 x = *(float2*)(p + lane * 2);

    float sum = x.x + x.y;
    float sq  = x.x * x.x + x.y * x.y;
#pragma unroll
    for (int off = 1; off < 64; off <<= 1) {
        sum += __shfl_xor(sum, off, 64);
        sq  += __shfl_xor(sq,  off, 64);
    }
    const float mu   = sum * (1.0f / 128.0f);
    const float var  = sq * (1.0f / 128.0f) - mu * mu;
    const float rstd = rsqrtf(var + 1e-5f);
    float y0 = (x.x - mu) * rstd;
    float y1 = (x.y - mu) * rstd;

    if (s >= S_TXT) {
        const int ip = s - S_TXT;
        const float c  = cost[ip * 64 + lane];
        const float sn = sint[ip * 64 + lane];
        const float o0 = y0 * c - y1 * sn;
        const float o1 = y1 * c + y0 * sn;
        y0 = o0; y1 = o1;
    }
    *(float2*)(p + lane * 2) = make_float2(y0, y1);
}

// ---------------------------------------------------------------------------
// Flash attention, fp32. Block = (head, 32-query tile). K-blocks of 64.
// K and V time-share one 64x128 LDS buffer. Online softmax in registers.
// Thread (sy,sx): score rows sy*2..+1, score cols sx*4..+3, O cols sx*8..+7.
// ---------------------------------------------------------------------------
__global__ __launch_bounds__(256) void attn_kernel(
    const float* __restrict__ qkv, float* __restrict__ out)
{
    __shared__ float Qs[32][HD + 4];    // 16.9 KB
    __shared__ float KVs[64][HD + 4];   // 33.8 KB
    __shared__ float Ps[32][68];        //  8.7 KB

    const int h  = blockIdx.y;
    const int q0 = blockIdx.x * 32;
    const int tid = threadIdx.x;
    const int sx = tid & 15;
    const int sy = tid >> 4;
    const float scale = 0.08838834764831845f;   // 1/sqrt(128)

    // load Q tile: thread -> row t>>3 (0..31), 16 floats at col (t&7)*16
    {
        const int row = tid >> 3;
        const int c0  = (tid & 7) * 16;
        const float* src = qkv + (size_t)(q0 + row) * QKV_N + h * HD + c0;
#pragma unroll
        for (int j = 0; j < 4; ++j)
            *(float4*)&Qs[row][c0 + 4 * j] = *(const float4*)(src + 4 * j);
    }

    float o[2][8] = {};
    float m[2] = {-INFINITY, -INFINITY};
    float l[2] = {0.0f, 0.0f};

    const int krow = tid >> 2;          // 0..63
    const int kc0  = (tid & 3) * 32;    // 0,32,64,96

    for (int kb = 0; kb < S_TOT / 64; ++kb) {
        // ---- load K block into KVs ----
        {
            const float* src = qkv + (size_t)(kb * 64 + krow) * QKV_N + DIMC + h * HD + kc0;
#pragma unroll
            for (int j = 0; j < 8; ++j)
                *(float4*)&KVs[krow][kc0 + 4 * j] = *(const float4*)(src + 4 * j);
        }
        __syncthreads();

        // ---- scores (registers) ----
        float sc[2][4] = {};
        for (int d = 0; d < HD; d += 4) {
            float4 qa = *(const float4*)&Qs[sy * 2 + 0][d];
            float4 qb = *(const float4*)&Qs[sy * 2 + 1][d];
#pragma unroll
            for (int j = 0; j < 4; ++j) {
                float4 kv = *(const float4*)&KVs[sx * 4 + j][d];
                sc[0][j] += qa.x * kv.x + qa.y * kv.y + qa.z * kv.z + qa.w * kv.w;
                sc[1][j] += qb.x * kv.x + qb.y * kv.y + qb.z * kv.z + qb.w * kv.w;
            }
        }

        // ---- online softmax update ----
        float p[2][4];
#pragma unroll
        for (int i = 0; i < 2; ++i) {
#pragma unroll
            for (int j = 0; j < 4; ++j) sc[i][j] *= scale;
            float rm = fmaxf(fmaxf(sc[i][0], sc[i][1]), fmaxf(sc[i][2], sc[i][3]));
#pragma unroll
            for (int off = 1; off < 16; off <<= 1)
                rm = fmaxf(rm, __shfl_xor(rm, off, 64));
            const float mn = fmaxf(m[i], rm);
            float rs = 0.0f;
#pragma unroll
            for (int j = 0; j < 4; ++j) {
                p[i][j] = __expf(sc[i][j] - mn);
                rs += p[i][j];
            }
#pragma unroll
            for (int off = 1; off < 16; off <<= 1)
                rs += __shfl_xor(rs, off, 64);
            const float alpha = __expf(m[i] - mn);
            l[i] = l[i] * alpha + rs;
            m[i] = mn;
#pragma unroll
            for (int j = 0; j < 8; ++j) o[i][j] *= alpha;
        }

        // publish P
#pragma unroll
        for (int i = 0; i < 2; ++i)
#pragma unroll
            for (int j = 0; j < 4; ++j)
                Ps[sy * 2 + i][sx * 4 + j] = p[i][j];

        __syncthreads();   // done reading K, done writing P

        // ---- load V block into KVs (overwrite K) ----
        {
            const float* src = qkv + (size_t)(kb * 64 + krow) * QKV_N + 2 * DIMC + h * HD + kc0;
#pragma unroll
            for (int j = 0; j < 8; ++j)
                *(float4*)&KVs[krow][kc0 + 4 * j] = *(const float4*)(src + 4 * j);
        }
        __syncthreads();

        // ---- O += P @ V ----
#pragma unroll 4
        for (int kk = 0; kk < 64; ++kk) {
            const float p0 = Ps[sy * 2 + 0][kk];
            const float p1 = Ps[sy * 2 + 1][kk];
            float4 v0 = *(const float4*)&KVs[kk][sx * 8];
            float4 v1 = *(const float4*)&KVs[kk][sx * 8 + 4];
            o[0][0] += p0 * v0.x; o[0][1] += p0 * v0.y; o[0][2] += p0 * v0.z; o[0][3] += p0 * v0.w;
            o[0][4] += p0 * v1.x; o[0][5] += p0 * v1.y; o[0][6] += p0 * v1.z; o[0][7] += p0 * v1.w;
            o[1][0] += p1 * v0.x; o[1][1] += p1 * v0.y; o[1][2] += p1 * v0.z; o[1][3] += p1 * v0.w;
            o[1][4] += p1 * v1.x; o[1][5] += p1 * v1.y; o[1][6] += p1 * v1.z; o[1][7] += p1 * v1.w;
        }
        __syncthreads();   // before next K load overwrites KVs
    }

    // epilogue: divide by l, write attn_out[s][h*128 + c]
#pragma unroll
    for (int i = 0; i < 2; ++i) {
        const float inv = 1.0f / l[i];
        float* dst = out + (size_t)(q0 + sy * 2 + i) * DIMC + h * HD + sx * 8;
#pragma unroll
        for (int j = 0; j < 8; ++j) dst[j] = o[i][j] * inv;
    }
}

// ---------------------------------------------------------------------------
// Output GEMM: out = attn_out @ Wout + bout, rows remapped:
//   r < 256   -> encoder_out, at d_out offset (2048 + r)*3072
//   r >= 256  -> hidden_out,  at d_out offset (r-256)*3072
// ---------------------------------------------------------------------------
__global__ __launch_bounds__(256) void out_gemm(
    const float* __restrict__ A, const float* __restrict__ W,
    const float* __restrict__ bias, float* __restrict__ out)
{
    const int K = DIMC, N = DIMC;
    __shared__ float As[16][68];
    __shared__ float Bs[16][68];
    const int bm = blockIdx.y * 64;
    const int bn = blockIdx.x * 64;
    const int tid = threadIdx.x;
    const int tx = tid & 15, ty = tid >> 4;

    const int ra = tid >> 2;
    const int ca = (tid & 3) * 4;
    const float* Arow = A + (size_t)(bm + ra) * K;
    const int rb = tid >> 4;
    const int cb = (tid & 15) * 4;

    float acc[4][4] = {};

    for (int k0 = 0; k0 < K; k0 += 16) {
        float4 av = *(const float4*)(Arow + k0 + ca);
        float4 bv = *(const float4*)(W + (size_t)(k0 + rb) * N + bn + cb);
        As[ca + 0][ra] = av.x;
        As[ca + 1][ra] = av.y;
        As[ca + 2][ra] = av.z;
        As[ca + 3][ra] = av.w;
        *(float4*)&Bs[rb][cb] = bv;
        __syncthreads();
#pragma unroll
        for (int kk = 0; kk < 16; ++kk) {
            float4 a = *(const float4*)&As[kk][ty * 4];
            float4 b = *(const float4*)&Bs[kk][tx * 4];
            float aa[4] = {a.x, a.y, a.z, a.w};
            float bb[4] = {b.x, b.y, b.z, b.w};
#pragma unroll
            for (int i = 0; i < 4; ++i)
#pragma unroll
                for (int j = 0; j < 4; ++j)
                    acc[i][j] += aa[i] * bb[j];
        }
        __syncthreads();
    }

#pragma unroll
    for (int i = 0; i < 4; ++i) {
        const int r = bm + ty * 4 + i;
        float* dst = (r < S_TXT)
                   ? (out + (size_t)(S_IMG + r) * DIMC + bn + tx * 4)
                   : (out + (size_t)(r - S_TXT) * DIMC + bn + tx * 4);
        float4 o;
        o.x = acc[i][0] + bias[bn + tx * 4 + 0];
        o.y = acc[i][1] + bias[bn + tx * 4 + 1];
        o.z = acc[i][2] + bias[bn + tx * 4 + 2];
        o.w = acc[i][3] + bias[bn + tx * 4 + 3];
        *(float4*)dst = o;
    }
}

// ---------------------------------------------------------------------------
extern "C" void kernel_launch(void* const* d_in, const int* in_sizes, int n_in,
                              void* d_out, int out_size, void* d_ws, size_t ws_size,
                              hipStream_t stream)
{
    const float* hid  = (const float*)d_in[0];   // (1,2048,3072)
    const float* enc  = (const float*)d_in[1];   // (1,256,3072)
    const float* cost = (const float*)d_in[2];   // (2048,64)
    const float* sint = (const float*)d_in[3];   // (2048,64)
    const float* Wqkv = (const float*)d_in[4];   // (3072,9216)
    const float* bqkv = (const float*)d_in[5];   // (9216)
    const float* Wout = (const float*)d_in[6];   // (3072,3072)
    const float* bout = (const float*)d_in[7];   // (3072)
    float* out = (float*)d_out;                  // hidden (2048x3072) then encoder (256x3072)

    float* qkv      = (float*)d_ws;                       // 2304*9216 f32
    float* attn_out = qkv + (size_t)S_TOT * QKV_N;        // 2304*3072 f32

    qkv_gemm<<<dim3(QKV_N / 64, S_TOT / 64), 256, 0, stream>>>(enc, hid, Wqkv, bqkv, qkv);
    ln_rope<<<(S_TOT * NH * 2) / 4, 256, 0, stream>>>(qkv, cost, sint);
    attn_kernel<<<dim3(S_TOT / 32, NH), 256, 0, stream>>>(qkv, attn_out);
    out_gemm<<<dim3(DIMC / 64, S_TOT / 64), 256, 0, stream>>>(attn_out, Wout, bout, out);
}

// Round 2
// 1087.220 us; speedup vs baseline: 4.1294x; 4.1294x over previous
//
#include <hip/hip_runtime.h>

#define DIMC 3072
#define NH 24
#define HD 128
#define QKV_N 9216
#define S_TXT 256
#define S_IMG 2048
#define S_TOT 2304

typedef _Float16 f16x8 __attribute__((ext_vector_type(8)));
typedef _Float16 f16x4 __attribute__((ext_vector_type(4)));
typedef _Float16 f16x2 __attribute__((ext_vector_type(2)));
typedef float f32x4 __attribute__((ext_vector_type(4)));

#define MFMA(A, B, C) __builtin_amdgcn_mfma_f32_16x16x32_f16(A, B, C, 0, 0, 0)

__device__ __forceinline__ void split1(float x, _Float16& h, _Float16& l) {
    h = (_Float16)x;
    l = (_Float16)(x - (float)h);
}

// ---------------------------------------------------------------------------
// concat(enc,hid) -> hi/lo fp16   (row per block)
// ---------------------------------------------------------------------------
__global__ __launch_bounds__(256) void split_x(
    const float* __restrict__ enc, const float* __restrict__ hid,
    _Float16* __restrict__ xh, _Float16* __restrict__ xl)
{
    const int s = blockIdx.x;
    const float* src = (s < S_TXT) ? enc + (size_t)s * DIMC
                                   : hid + (size_t)(s - S_TXT) * DIMC;
    const int t = threadIdx.x;
#pragma unroll
    for (int it = 0; it < 3; ++it) {
        const int i = (it * 256 + t) * 4;
        float4 v = *(const float4*)(src + i);
        _Float16 h0,l0,h1,l1,h2,l2,h3,l3;
        split1(v.x,h0,l0); split1(v.y,h1,l1); split1(v.z,h2,l2); split1(v.w,h3,l3);
        f16x4 hv; hv.x=h0; hv.y=h1; hv.z=h2; hv.w=h3;
        f16x4 lv; lv.x=l0; lv.y=l1; lv.z=l2; lv.w=l3;
        *(f16x4*)(xh + (size_t)s * DIMC + i) = hv;
        *(f16x4*)(xl + (size_t)s * DIMC + i) = lv;
    }
}

// attn_out (f32, contiguous) -> hi/lo fp16
__global__ __launch_bounds__(256) void split_ao(
    const float* __restrict__ src0,
    _Float16* __restrict__ xh, _Float16* __restrict__ xl)
{
    const int s = blockIdx.x;
    const float* src = src0 + (size_t)s * DIMC;
    const int t = threadIdx.x;
#pragma unroll
    for (int it = 0; it < 3; ++it) {
        const int i = (it * 256 + t) * 4;
        float4 v = *(const float4*)(src + i);
        _Float16 h0,l0,h1,l1,h2,l2,h3,l3;
        split1(v.x,h0,l0); split1(v.y,h1,l1); split1(v.z,h2,l2); split1(v.w,h3,l3);
        f16x4 hv; hv.x=h0; hv.y=h1; hv.z=h2; hv.w=h3;
        f16x4 lv; lv.x=l0; lv.y=l1; lv.z=l2; lv.w=l3;
        *(f16x4*)(xh + (size_t)s * DIMC + i) = hv;
        *(f16x4*)(xl + (size_t)s * DIMC + i) = lv;
    }
}

// ---------------------------------------------------------------------------
// W [3072 k][ldw] f32 (column window of 3072) -> Wt hi/lo [n][3072 k] fp16
// ---------------------------------------------------------------------------
__global__ __launch_bounds__(256) void transpose_split_w(
    const float* __restrict__ W, const int ldw,
    _Float16* __restrict__ Th, _Float16* __restrict__ Tl)
{
    __shared__ float T[64][68];
    const int n0 = blockIdx.x * 64, k0 = blockIdx.y * 64;
    const int t = threadIdx.x;
    {
        const int r = t >> 2, c4 = (t & 3) * 16;
#pragma unroll
        for (int j = 0; j < 4; ++j) {
            float4 v = *(const float4*)(W + (size_t)(k0 + r) * ldw + n0 + c4 + j * 4);
            *(float4*)&T[r][c4 + j * 4] = v;
        }
    }
    __syncthreads();
    const int nr = t >> 2, kp = (t & 3) * 16;
    f16x8 hv0, hv1, lv0, lv1;
#pragma unroll
    for (int j = 0; j < 8; ++j) {
        _Float16 hh, ll;
        split1(T[kp + j][nr], hh, ll);
        hv0[j] = hh; lv0[j] = ll;
    }
#pragma unroll
    for (int j = 0; j < 8; ++j) {
        _Float16 hh, ll;
        split1(T[kp + 8 + j][nr], hh, ll);
        hv1[j] = hh; lv1[j] = ll;
    }
    _Float16* dh = Th + (size_t)(n0 + nr) * DIMC + k0 + kp;
    _Float16* dl = Tl + (size_t)(n0 + nr) * DIMC + k0 + kp;
    *(f16x8*)(dh) = hv0; *(f16x8*)(dh + 8) = hv1;
    *(f16x8*)(dl) = lv0; *(f16x8*)(dl + 8) = lv1;
}

// ---------------------------------------------------------------------------
// GEMM: C[2304][Nchunk=3072] = A(2304x3072) @ B(3072x3072) + bias
// A hi/lo [m][k], B hi/lo [n][k] (pre-transposed). 3-term fp16 MFMA.
// 128x128 tile, BK=32, 4 waves (2x2), 4x4 16x16x32 frags per wave.
// ---------------------------------------------------------------------------
template <int REMAP>
__global__ __launch_bounds__(256) void gemm_f16_3t(
    const _Float16* __restrict__ Ah, const _Float16* __restrict__ Al,
    const _Float16* __restrict__ Bh, const _Float16* __restrict__ Bl,
    const float* __restrict__ bias, float* __restrict__ C, const int ldc)
{
    __shared__ __attribute__((aligned(16))) _Float16 Ash[128][40];
    __shared__ __attribute__((aligned(16))) _Float16 Asl[128][40];
    __shared__ __attribute__((aligned(16))) _Float16 Bsh[128][40];
    __shared__ __attribute__((aligned(16))) _Float16 Bsl[128][40];

    const int tid = threadIdx.x;
    const int l = tid & 63, w = tid >> 6;
    const int wr = w >> 1, wc = w & 1;
    const int lr = l & 15, lk = (l >> 4) * 8;
    const int bm = blockIdx.y * 128, bn = blockIdx.x * 128;
    const int srow = tid >> 1, shalf = (tid & 1) * 16;

    const _Float16* gAh = Ah + (size_t)(bm + srow) * DIMC + shalf;
    const _Float16* gAl = Al + (size_t)(bm + srow) * DIMC + shalf;
    const _Float16* gBh = Bh + (size_t)(bn + srow) * DIMC + shalf;
    const _Float16* gBl = Bl + (size_t)(bn + srow) * DIMC + shalf;

    f32x4 acc[4][4] = {};
    uint4 rA0, rA1, rA2, rA3, rB0, rB1, rB2, rB3;

#define LOADT(k0) { \
    rA0 = *(const uint4*)(gAh + (k0));     rA1 = *(const uint4*)(gAh + (k0) + 8); \
    rA2 = *(const uint4*)(gAl + (k0));     rA3 = *(const uint4*)(gAl + (k0) + 8); \
    rB0 = *(const uint4*)(gBh + (k0));     rB1 = *(const uint4*)(gBh + (k0) + 8); \
    rB2 = *(const uint4*)(gBl + (k0));     rB3 = *(const uint4*)(gBl + (k0) + 8); }

    LOADT(0);
    for (int k0 = 0; k0 < DIMC; k0 += 32) {
        __syncthreads();
        *(uint4*)&Ash[srow][shalf] = rA0; *(uint4*)&Ash[srow][shalf + 8] = rA1;
        *(uint4*)&Asl[srow][shalf] = rA2; *(uint4*)&Asl[srow][shalf + 8] = rA3;
        *(uint4*)&Bsh[srow][shalf] = rB0; *(uint4*)&Bsh[srow][shalf + 8] = rB1;
        *(uint4*)&Bsl[srow][shalf] = rB2; *(uint4*)&Bsl[srow][shalf + 8] = rB3;
        __syncthreads();
        if (k0 + 32 < DIMC) LOADT(k0 + 32);

        f16x8 bhf[4], blf[4];
#pragma unroll
        for (int ni = 0; ni < 4; ++ni) {
            bhf[ni] = *(const f16x8*)&Bsh[wc * 64 + ni * 16 + lr][lk];
            blf[ni] = *(const f16x8*)&Bsl[wc * 64 + ni * 16 + lr][lk];
        }
#pragma unroll
        for (int mi = 0; mi < 4; ++mi) {
            f16x8 ahf = *(const f16x8*)&Ash[wr * 64 + mi * 16 + lr][lk];
            f16x8 alf = *(const f16x8*)&Asl[wr * 64 + mi * 16 + lr][lk];
#pragma unroll
            for (int ni = 0; ni < 4; ++ni) {
                acc[mi][ni] = MFMA(ahf, bhf[ni], acc[mi][ni]);
                acc[mi][ni] = MFMA(ahf, blf[ni], acc[mi][ni]);
                acc[mi][ni] = MFMA(alf, bhf[ni], acc[mi][ni]);
            }
        }
    }
#undef LOADT

#pragma unroll
    for (int mi = 0; mi < 4; ++mi)
#pragma unroll
        for (int ni = 0; ni < 4; ++ni) {
            const int cl = bn + wc * 64 + ni * 16 + lr;
            const float bv = bias[cl];
#pragma unroll
            for (int e = 0; e < 4; ++e) {
                const int r = bm + wr * 64 + mi * 16 + (l >> 4) * 4 + e;
                const float v = acc[mi][ni][e] + bv;
                if (REMAP) {
                    const int gr = (r < S_TXT) ? (S_IMG + r) : (r - S_TXT);
                    C[(size_t)gr * DIMC + cl] = v;
                } else {
                    C[(size_t)r * ldc + cl] = v;
                }
            }
        }
}

// ---------------------------------------------------------------------------
// LayerNorm + RoPE on q,k rows of qkv; writes per-head hi/lo fp16 Q,K arrays
// [NH][S][128]. One wave per (s, q/k, head).
// ---------------------------------------------------------------------------
__global__ __launch_bounds__(256) void ln_rope_split(
    const float* __restrict__ qkv,
    const float* __restrict__ cost, const float* __restrict__ sint,
    _Float16* __restrict__ Qh, _Float16* __restrict__ Ql,
    _Float16* __restrict__ Kh, _Float16* __restrict__ Kl)
{
    const int wave = threadIdx.x >> 6;
    const int lane = threadIdx.x & 63;
    const int task = blockIdx.x * 4 + wave;
    const int s = task / 48;
    const int rem = task % 48;
    const int qk = rem / 24;
    const int h = rem % 24;

    const float* p = qkv + (size_t)s * QKV_N + qk * DIMC + h * HD;
    float2 x = *(const float2*)(p + lane * 2);

    float sum = x.x + x.y;
    float sq = x.x * x.x + x.y * x.y;
#pragma unroll
    for (int off = 1; off < 64; off <<= 1) {
        sum += __shfl_xor(sum, off, 64);
        sq  += __shfl_xor(sq, off, 64);
    }
    const float mu = sum * (1.0f / 128.0f);
    const float var = sq * (1.0f / 128.0f) - mu * mu;
    const float rstd = rsqrtf(var + 1e-5f);
    float y0 = (x.x - mu) * rstd;
    float y1 = (x.y - mu) * rstd;

    if (s >= S_TXT) {
        const int ip = s - S_TXT;
        const float c = cost[ip * 64 + lane];
        const float sn = sint[ip * 64 + lane];
        const float o0 = y0 * c - y1 * sn;
        const float o1 = y1 * c + y0 * sn;
        y0 = o0; y1 = o1;
    }

    _Float16 h0, l0, h1, l1;
    split1(y0, h0, l0); split1(y1, h1, l1);
    const size_t off = ((size_t)h * S_TOT + s) * HD + lane * 2;
    _Float16* dh = (qk ? Kh : Qh) + off;
    _Float16* dl = (qk ? Kl : Ql) + off;
    f16x2 hv; hv.x = h0; hv.y = h1;
    f16x2 lv; lv.x = l0; lv.y = l1;
    *(f16x2*)dh = hv;
    *(f16x2*)dl = lv;
}

// ---------------------------------------------------------------------------
// V: qkv[s][2*3072 + h*128 + d] -> transposed hi/lo Vt [NH][128][S]
// ---------------------------------------------------------------------------
__global__ __launch_bounds__(256) void v_split_transpose(
    const float* __restrict__ qkv,
    _Float16* __restrict__ Vth, _Float16* __restrict__ Vtl)
{
    __shared__ float T[64][132];
    const int h = blockIdx.y;
    const int s0 = blockIdx.x * 64;
    const int t = threadIdx.x;
    {
        const int sl = t >> 2, dp = (t & 3) * 32;
#pragma unroll
        for (int j = 0; j < 8; ++j) {
            float4 v = *(const float4*)(qkv + (size_t)(s0 + sl) * QKV_N + 2 * DIMC + h * HD + dp + j * 4);
            *(float4*)&T[sl][dp + j * 4] = v;
        }
    }
    __syncthreads();
    const int d = t >> 1, sh = (t & 1) * 32;
    f16x8 hv[4], lv[4];
#pragma unroll
    for (int ss = 0; ss < 32; ++ss) {
        _Float16 hh, ll;
        split1(T[sh + ss][d], hh, ll);
        hv[ss >> 3][ss & 7] = hh;
        lv[ss >> 3][ss & 7] = ll;
    }
    _Float16* bh = Vth + ((size_t)h * HD + d) * S_TOT + s0 + sh;
    _Float16* bl = Vtl + ((size_t)h * HD + d) * S_TOT + s0 + sh;
#pragma unroll
    for (int j = 0; j < 4; ++j) {
        *(f16x8*)(bh + j * 8) = hv[j];
        *(f16x8*)(bl + j * 8) = lv[j];
    }
}

// ---------------------------------------------------------------------------
// Flash attention, fp16 3-term MFMA. Block = (64 q-rows, head), 4 waves.
// Swapped scores S^T = K @ Q^T (lane-local softmax stats), KV blocks of 32.
// ---------------------------------------------------------------------------
__global__ __launch_bounds__(256) void attn_mfma(
    const _Float16* __restrict__ Qh_g, const _Float16* __restrict__ Ql_g,
    const _Float16* __restrict__ Kh_g, const _Float16* __restrict__ Kl_g,
    const _Float16* __restrict__ Vh_g, const _Float16* __restrict__ Vl_g,
    float* __restrict__ aout)
{
    __shared__ __attribute__((aligned(16))) _Float16 Ksh[4][32][40];
    __shared__ __attribute__((aligned(16))) _Float16 Ksl[4][32][40];
    __shared__ __attribute__((aligned(16))) _Float16 Vsh[128][40];
    __shared__ __attribute__((aligned(16))) _Float16 Vsl[128][40];
    __shared__ __attribute__((aligned(16))) _Float16 Pah[4][16][40];
    __shared__ __attribute__((aligned(16))) _Float16 Pal[4][16][40];

    const int h = blockIdx.y;
    const int q0 = blockIdx.x * 64;
    const int tid = threadIdx.x;
    const int w = tid >> 6, l = tid & 63;
    const int lr = l & 15, g = l >> 4, lk = g * 8;
    const float scale = 0.08838834764831845f;

    // Q fragments in registers (B-operand of swapped QK^T)
    const int qrow = q0 + w * 16 + lr;
    const _Float16* qbh = Qh_g + ((size_t)h * S_TOT + qrow) * HD + lk;
    const _Float16* qbl = Ql_g + ((size_t)h * S_TOT + qrow) * HD + lk;
    f16x8 qh[4], ql[4];
#pragma unroll
    for (int db = 0; db < 4; ++db) {
        qh[db] = *(const f16x8*)(qbh + db * 32);
        ql[db] = *(const f16x8*)(qbl + db * 32);
    }

    f32x4 o[8] = {};
    float mrow = -3.0e38f, lrow = 0.0f;

    // staging assignments
    const int kr = tid >> 3, kdg = tid & 7, kdb = kdg >> 1, kco = (kdg & 1) * 16;
    const int vd = tid >> 1, vpt = (tid & 1) * 16;
    const _Float16* gKh = Kh_g + ((size_t)h * S_TOT + kr) * HD + kdg * 16;
    const _Float16* gKl = Kl_g + ((size_t)h * S_TOT + kr) * HD + kdg * 16;
    const _Float16* gVh = Vh_g + ((size_t)h * HD + vd) * S_TOT + vpt;
    const _Float16* gVl = Vl_g + ((size_t)h * HD + vd) * S_TOT + vpt;

    uint4 rK0, rK1, rK2, rK3, rV0, rV1, rV2, rV3;
#define LOADKV(kv0) { \
    rK0 = *(const uint4*)(gKh + (size_t)(kv0) * HD); rK1 = *(const uint4*)(gKh + (size_t)(kv0) * HD + 8); \
    rK2 = *(const uint4*)(gKl + (size_t)(kv0) * HD); rK3 = *(const uint4*)(gKl + (size_t)(kv0) * HD + 8); \
    rV0 = *(const uint4*)(gVh + (kv0)); rV1 = *(const uint4*)(gVh + (kv0) + 8); \
    rV2 = *(const uint4*)(gVl + (kv0)); rV3 = *(const uint4*)(gVl + (kv0) + 8); }

    LOADKV(0);

    for (int kb = 0; kb < S_TOT / 32; ++kb) {
        __syncthreads();
        *(uint4*)&Ksh[kdb][kr][kco] = rK0; *(uint4*)&Ksh[kdb][kr][kco + 8] = rK1;
        *(uint4*)&Ksl[kdb][kr][kco] = rK2; *(uint4*)&Ksl[kdb][kr][kco + 8] = rK3;
        *(uint4*)&Vsh[vd][vpt] = rV0; *(uint4*)&Vsh[vd][vpt + 8] = rV1;
        *(uint4*)&Vsl[vd][vpt] = rV2; *(uint4*)&Vsl[vd][vpt + 8] = rV3;
        __syncthreads();
        if (kb + 1 < S_TOT / 32) LOADKV((kb + 1) * 32);

        // scores S^T (2 frags of 16kv x 16q), 3-term
        f32x4 sT[2] = {};
#pragma unroll
        for (int db = 0; db < 4; ++db)
#pragma unroll
            for (int mf = 0; mf < 2; ++mf) {
                f16x8 kh_ = *(const f16x8*)&Ksh[db][mf * 16 + lr][lk];
                f16x8 kl_ = *(const f16x8*)&Ksl[db][mf * 16 + lr][lk];
                sT[mf] = MFMA(kh_, qh[db], sT[mf]);
                sT[mf] = MFMA(kh_, ql[db], sT[mf]);
                sT[mf] = MFMA(kl_, qh[db], sT[mf]);
            }

        // online softmax (stats per lane for q = lr)
        float sc_[2][4];
        float pm = -3.0e38f;
#pragma unroll
        for (int mf = 0; mf < 2; ++mf)
#pragma unroll
            for (int e = 0; e < 4; ++e) {
                const float s = sT[mf][e] * scale;
                sc_[mf][e] = s;
                pm = fmaxf(pm, s);
            }
        pm = fmaxf(pm, __shfl_xor(pm, 16, 64));
        pm = fmaxf(pm, __shfl_xor(pm, 32, 64));
        const float mnew = fmaxf(mrow, pm);
        float rs = 0.0f;
        float ex_[2][4];
#pragma unroll
        for (int mf = 0; mf < 2; ++mf)
#pragma unroll
            for (int e = 0; e < 4; ++e) {
                const float pv = __expf(sc_[mf][e] - mnew);
                ex_[mf][e] = pv;
                rs += pv;
            }
        rs += __shfl_xor(rs, 16, 64);
        rs += __shfl_xor(rs, 32, 64);
        const float alpha = __expf(mrow - mnew);
        lrow = lrow * alpha + rs;
        mrow = mnew;

        // rescale O (O rows are q = g*4+e; alpha held at lane == q)
        const float a0 = __shfl(alpha, g * 4 + 0, 64);
        const float a1 = __shfl(alpha, g * 4 + 1, 64);
        const float a2 = __shfl(alpha, g * 4 + 2, 64);
        const float a3 = __shfl(alpha, g * 4 + 3, 64);
#pragma unroll
        for (int df = 0; df < 8; ++df) {
            o[df][0] *= a0; o[df][1] *= a1; o[df][2] *= a2; o[df][3] *= a3;
        }

        // publish P (hi/lo) into per-wave LDS slice, layout [q][kv]
#pragma unroll
        for (int mf = 0; mf < 2; ++mf) {
            _Float16 h0,l0,h1,l1,h2,l2,h3,l3;
            split1(ex_[mf][0], h0, l0); split1(ex_[mf][1], h1, l1);
            split1(ex_[mf][2], h2, l2); split1(ex_[mf][3], h3, l3);
            const int kvb = mf * 16 + g * 4;
            f16x2 t0; t0.x = h0; t0.y = h1;
            f16x2 t1; t1.x = h2; t1.y = h3;
            f16x2 t2; t2.x = l0; t2.y = l1;
            f16x2 t3; t3.x = l2; t3.y = l3;
            *(f16x2*)&Pah[w][lr][kvb] = t0;
            *(f16x2*)&Pah[w][lr][kvb + 2] = t1;
            *(f16x2*)&Pal[w][lr][kvb] = t2;
            *(f16x2*)&Pal[w][lr][kvb + 2] = t3;
        }

        // PV: O(16q x 128d) += P(16x32) @ V(32x128), 3-term
        f16x8 pah = *(const f16x8*)&Pah[w][lr][lk];
        f16x8 pal = *(const f16x8*)&Pal[w][lr][lk];
#pragma unroll
        for (int df = 0; df < 8; ++df) {
            f16x8 vh_ = *(const f16x8*)&Vsh[df * 16 + lr][lk];
            f16x8 vl_ = *(const f16x8*)&Vsl[df * 16 + lr][lk];
            o[df] = MFMA(pah, vh_, o[df]);
            o[df] = MFMA(pah, vl_, o[df]);
            o[df] = MFMA(pal, vh_, o[df]);
        }
    }
#undef LOADKV

    const float inv = 1.0f / lrow;
    const float b0 = __shfl(inv, g * 4 + 0, 64);
    const float b1 = __shfl(inv, g * 4 + 1, 64);
    const float b2 = __shfl(inv, g * 4 + 2, 64);
    const float b3 = __shfl(inv, g * 4 + 3, 64);
    const float bb[4] = {b0, b1, b2, b3};
#pragma unroll
    for (int df = 0; df < 8; ++df)
#pragma unroll
        for (int e = 0; e < 4; ++e) {
            const int r = q0 + w * 16 + g * 4 + e;
            aout[(size_t)r * DIMC + h * HD + df * 16 + lr] = o[df][e] * bb[e];
        }
}

// ---------------------------------------------------------------------------
extern "C" void kernel_launch(void* const* d_in, const int* in_sizes, int n_in,
                              void* d_out, int out_size, void* d_ws, size_t ws_size,
                              hipStream_t stream)
{
    const float* hid  = (const float*)d_in[0];
    const float* enc  = (const float*)d_in[1];
    const float* cost = (const float*)d_in[2];
    const float* sint = (const float*)d_in[3];
    const float* Wqkv = (const float*)d_in[4];
    const float* bqkv = (const float*)d_in[5];
    const float* Wout = (const float*)d_in[6];
    const float* bout = (const float*)d_in[7];
    float* out = (float*)d_out;

    char* ws = (char*)d_ws;
    float*    qkv  = (float*)(ws + 0);                  // 2304x9216 f32 (84.9 MB)
    float*    aout = (float*)(ws + 0);                  // reuse after qkv dead
    _Float16* aoh  = (_Float16*)(ws + 28311552);
    _Float16* aol  = (_Float16*)(ws + 42467328);
    _Float16* xh   = (_Float16*)(ws + 84934656);
    _Float16* xl   = (_Float16*)(ws + 99090432);
    _Float16* Wth  = (_Float16*)(ws + 113246208);
    _Float16* Wtl  = (_Float16*)(ws + 132120576);
    // phase 2 (over x/Wt regions, dead after qkv gemm):
    _Float16* Qh   = (_Float16*)(ws + 84934656);
    _Float16* Ql   = (_Float16*)(ws + 99090432);
    _Float16* Kh   = (_Float16*)(ws + 113246208);
    _Float16* Kl   = (_Float16*)(ws + 127401984);
    _Float16* Vth  = (_Float16*)(ws + 141557760);
    _Float16* Vtl  = (_Float16*)(ws + 155713536);
    // phase 3 (over Q/K, dead after attn):
    _Float16* W2h  = (_Float16*)(ws + 84934656);
    _Float16* W2l  = (_Float16*)(ws + 103809024);

    split_x<<<S_TOT, 256, 0, stream>>>(enc, hid, xh, xl);
    for (int c = 0; c < 3; ++c) {
        transpose_split_w<<<dim3(48, 48), 256, 0, stream>>>(Wqkv + c * DIMC, QKV_N, Wth, Wtl);
        gemm_f16_3t<0><<<dim3(24, 18), 256, 0, stream>>>(
            xh, xl, Wth, Wtl, bqkv + c * DIMC, qkv + c * DIMC, QKV_N);
    }
    ln_rope_split<<<(S_TOT * 48) / 4, 256, 0, stream>>>(qkv, cost, sint, Qh, Ql, Kh, Kl);
    v_split_transpose<<<dim3(36, 24), 256, 0, stream>>>(qkv, Vth, Vtl);
    attn_mfma<<<dim3(36, 24), 256, 0, stream>>>(Qh, Ql, Kh, Kl, Vth, Vtl, aout);
    split_ao<<<S_TOT, 256, 0, stream>>>(aout, aoh, aol);
    transpose_split_w<<<dim3(48, 48), 256, 0, stream>>>(Wout, DIMC, W2h, W2l);
    gemm_f16_3t<1><<<dim3(24, 18), 256, 0, stream>>>(
        aoh, aol, W2h, W2l, bout, out, DIMC);
}

// Round 3
// 767.314 us; speedup vs baseline: 5.8510x; 1.4169x over previous
//
#include <hip/hip_runtime.h>

#define DIMC 3072
#define NH 24
#define HD 128
#define QKV_N 9216
#define S_TXT 256
#define S_IMG 2048
#define S_TOT 2304

typedef _Float16 f16x8 __attribute__((ext_vector_type(8)));
typedef _Float16 f16x4 __attribute__((ext_vector_type(4)));
typedef _Float16 f16x2 __attribute__((ext_vector_type(2)));
typedef float f32x4 __attribute__((ext_vector_type(4)));

#define MFMA(A, B, C) __builtin_amdgcn_mfma_f32_16x16x32_f16(A, B, C, 0, 0, 0)

__device__ __forceinline__ void split1(float x, _Float16& h, _Float16& l) {
    h = (_Float16)x;
    l = (_Float16)(x - (float)h);
}

// ---------------------------------------------------------------------------
// concat(enc,hid) -> fp16 (hi only; 2-term QKV GEMM needs only x_hi)
// ---------------------------------------------------------------------------
__global__ __launch_bounds__(256) void split_x(
    const float* __restrict__ enc, const float* __restrict__ hid,
    _Float16* __restrict__ xh)
{
    const int s = blockIdx.x;
    const float* src = (s < S_TXT) ? enc + (size_t)s * DIMC
                                   : hid + (size_t)(s - S_TXT) * DIMC;
    const int t = threadIdx.x;
#pragma unroll
    for (int it = 0; it < 3; ++it) {
        const int i = (it * 256 + t) * 4;
        float4 v = *(const float4*)(src + i);
        f16x4 hv;
        hv.x = (_Float16)v.x; hv.y = (_Float16)v.y;
        hv.z = (_Float16)v.z; hv.w = (_Float16)v.w;
        *(f16x4*)(xh + (size_t)s * DIMC + i) = hv;
    }
}

// ---------------------------------------------------------------------------
// W [3072 k][ldw] f32 (column window of 3072) -> Wt hi/lo [n][3072 k] fp16
// ---------------------------------------------------------------------------
__global__ __launch_bounds__(256) void transpose_split_w(
    const float* __restrict__ W, const int ldw,
    _Float16* __restrict__ Th, _Float16* __restrict__ Tl)
{
    __shared__ float T[64][68];
    const int n0 = blockIdx.x * 64, k0 = blockIdx.y * 64;
    const int t = threadIdx.x;
    {
        const int r = t >> 2, c4 = (t & 3) * 16;
#pragma unroll
        for (int j = 0; j < 4; ++j) {
            float4 v = *(const float4*)(W + (size_t)(k0 + r) * ldw + n0 + c4 + j * 4);
            *(float4*)&T[r][c4 + j * 4] = v;
        }
    }
    __syncthreads();
    const int nr = t >> 2, kp = (t & 3) * 16;
    f16x8 hv0, hv1, lv0, lv1;
#pragma unroll
    for (int j = 0; j < 8; ++j) {
        _Float16 hh, ll;
        split1(T[kp + j][nr], hh, ll);
        hv0[j] = hh; lv0[j] = ll;
    }
#pragma unroll
    for (int j = 0; j < 8; ++j) {
        _Float16 hh, ll;
        split1(T[kp + 8 + j][nr], hh, ll);
        hv1[j] = hh; lv1[j] = ll;
    }
    _Float16* dh = Th + (size_t)(n0 + nr) * DIMC + k0 + kp;
    _Float16* dl = Tl + (size_t)(n0 + nr) * DIMC + k0 + kp;
    *(f16x8*)(dh) = hv0; *(f16x8*)(dh + 8) = hv1;
    *(f16x8*)(dl) = lv0; *(f16x8*)(dl + 8) = lv1;
}

// ---------------------------------------------------------------------------
// QKV GEMM, 2-term: C = Ah @ (Bh + Bl) + bias.  A fp16-hi only.
// 128x128 tile, BK=32, 4 waves (2x2), 4x4 16x16x32 frags per wave.
// ---------------------------------------------------------------------------
__global__ __launch_bounds__(256) void gemm_f16_2t(
    const _Float16* __restrict__ Ah,
    const _Float16* __restrict__ Bh, const _Float16* __restrict__ Bl,
    const float* __restrict__ bias, float* __restrict__ C, const int ldc)
{
    __shared__ __attribute__((aligned(16))) _Float16 Ash[128][40];
    __shared__ __attribute__((aligned(16))) _Float16 Bsh[128][40];
    __shared__ __attribute__((aligned(16))) _Float16 Bsl[128][40];

    const int tid = threadIdx.x;
    const int l = tid & 63, w = tid >> 6;
    const int wr = w >> 1, wc = w & 1;
    const int lr = l & 15, lk = (l >> 4) * 8;
    const int bm = blockIdx.y * 128, bn = blockIdx.x * 128;
    const int srow = tid >> 1, shalf = (tid & 1) * 16;

    const _Float16* gAh = Ah + (size_t)(bm + srow) * DIMC + shalf;
    const _Float16* gBh = Bh + (size_t)(bn + srow) * DIMC + shalf;
    const _Float16* gBl = Bl + (size_t)(bn + srow) * DIMC + shalf;

    f32x4 acc[4][4] = {};
    uint4 rA0, rA1, rB0, rB1, rB2, rB3;

#define LOADT(k0) { \
    rA0 = *(const uint4*)(gAh + (k0));     rA1 = *(const uint4*)(gAh + (k0) + 8); \
    rB0 = *(const uint4*)(gBh + (k0));     rB1 = *(const uint4*)(gBh + (k0) + 8); \
    rB2 = *(const uint4*)(gBl + (k0));     rB3 = *(const uint4*)(gBl + (k0) + 8); }

    LOADT(0);
    for (int k0 = 0; k0 < DIMC; k0 += 32) {
        __syncthreads();
        *(uint4*)&Ash[srow][shalf] = rA0; *(uint4*)&Ash[srow][shalf + 8] = rA1;
        *(uint4*)&Bsh[srow][shalf] = rB0; *(uint4*)&Bsh[srow][shalf + 8] = rB1;
        *(uint4*)&Bsl[srow][shalf] = rB2; *(uint4*)&Bsl[srow][shalf + 8] = rB3;
        __syncthreads();
        if (k0 + 32 < DIMC) LOADT(k0 + 32);

        f16x8 bhf[4], blf[4];
#pragma unroll
        for (int ni = 0; ni < 4; ++ni) {
            bhf[ni] = *(const f16x8*)&Bsh[wc * 64 + ni * 16 + lr][lk];
            blf[ni] = *(const f16x8*)&Bsl[wc * 64 + ni * 16 + lr][lk];
        }
#pragma unroll
        for (int mi = 0; mi < 4; ++mi) {
            f16x8 ahf = *(const f16x8*)&Ash[wr * 64 + mi * 16 + lr][lk];
#pragma unroll
            for (int ni = 0; ni < 4; ++ni) {
                acc[mi][ni] = MFMA(ahf, bhf[ni], acc[mi][ni]);
                acc[mi][ni] = MFMA(ahf, blf[ni], acc[mi][ni]);
            }
        }
    }
#undef LOADT

#pragma unroll
    for (int mi = 0; mi < 4; ++mi)
#pragma unroll
        for (int ni = 0; ni < 4; ++ni) {
            const int cl = bn + wc * 64 + ni * 16 + lr;
            const float bv = bias[cl];
#pragma unroll
            for (int e = 0; e < 4; ++e) {
                const int r = bm + wr * 64 + mi * 16 + (l >> 4) * 4 + e;
                C[(size_t)r * ldc + cl] = acc[mi][ni][e] + bv;
            }
        }
}

// ---------------------------------------------------------------------------
// Out-proj GEMM, 3-term (exact): C = (Ah+Al) @ (Bh+Bl) + bias, remapped rows.
// ---------------------------------------------------------------------------
__global__ __launch_bounds__(256) void gemm_f16_3t(
    const _Float16* __restrict__ Ah, const _Float16* __restrict__ Al,
    const _Float16* __restrict__ Bh, const _Float16* __restrict__ Bl,
    const float* __restrict__ bias, float* __restrict__ C)
{
    __shared__ __attribute__((aligned(16))) _Float16 Ash[128][40];
    __shared__ __attribute__((aligned(16))) _Float16 Asl[128][40];
    __shared__ __attribute__((aligned(16))) _Float16 Bsh[128][40];
    __shared__ __attribute__((aligned(16))) _Float16 Bsl[128][40];

    const int tid = threadIdx.x;
    const int l = tid & 63, w = tid >> 6;
    const int wr = w >> 1, wc = w & 1;
    const int lr = l & 15, lk = (l >> 4) * 8;
    const int bm = blockIdx.y * 128, bn = blockIdx.x * 128;
    const int srow = tid >> 1, shalf = (tid & 1) * 16;

    const _Float16* gAh = Ah + (size_t)(bm + srow) * DIMC + shalf;
    const _Float16* gAl = Al + (size_t)(bm + srow) * DIMC + shalf;
    const _Float16* gBh = Bh + (size_t)(bn + srow) * DIMC + shalf;
    const _Float16* gBl = Bl + (size_t)(bn + srow) * DIMC + shalf;

    f32x4 acc[4][4] = {};
    uint4 rA0, rA1, rA2, rA3, rB0, rB1, rB2, rB3;

#define LOADT(k0) { \
    rA0 = *(const uint4*)(gAh + (k0));     rA1 = *(const uint4*)(gAh + (k0) + 8); \
    rA2 = *(const uint4*)(gAl + (k0));     rA3 = *(const uint4*)(gAl + (k0) + 8); \
    rB0 = *(const uint4*)(gBh + (k0));     rB1 = *(const uint4*)(gBh + (k0) + 8); \
    rB2 = *(const uint4*)(gBl + (k0));     rB3 = *(const uint4*)(gBl + (k0) + 8); }

    LOADT(0);
    for (int k0 = 0; k0 < DIMC; k0 += 32) {
        __syncthreads();
        *(uint4*)&Ash[srow][shalf] = rA0; *(uint4*)&Ash[srow][shalf + 8] = rA1;
        *(uint4*)&Asl[srow][shalf] = rA2; *(uint4*)&Asl[srow][shalf + 8] = rA3;
        *(uint4*)&Bsh[srow][shalf] = rB0; *(uint4*)&Bsh[srow][shalf + 8] = rB1;
        *(uint4*)&Bsl[srow][shalf] = rB2; *(uint4*)&Bsl[srow][shalf + 8] = rB3;
        __syncthreads();
        if (k0 + 32 < DIMC) LOADT(k0 + 32);

        f16x8 bhf[4], blf[4];
#pragma unroll
        for (int ni = 0; ni < 4; ++ni) {
            bhf[ni] = *(const f16x8*)&Bsh[wc * 64 + ni * 16 + lr][lk];
            blf[ni] = *(const f16x8*)&Bsl[wc * 64 + ni * 16 + lr][lk];
        }
#pragma unroll
        for (int mi = 0; mi < 4; ++mi) {
            f16x8 ahf = *(const f16x8*)&Ash[wr * 64 + mi * 16 + lr][lk];
            f16x8 alf = *(const f16x8*)&Asl[wr * 64 + mi * 16 + lr][lk];
#pragma unroll
            for (int ni = 0; ni < 4; ++ni) {
                acc[mi][ni] = MFMA(ahf, bhf[ni], acc[mi][ni]);
                acc[mi][ni] = MFMA(ahf, blf[ni], acc[mi][ni]);
                acc[mi][ni] = MFMA(alf, bhf[ni], acc[mi][ni]);
            }
        }
    }
#undef LOADT

#pragma unroll
    for (int mi = 0; mi < 4; ++mi)
#pragma unroll
        for (int ni = 0; ni < 4; ++ni) {
            const int cl = bn + wc * 64 + ni * 16 + lr;
            const float bv = bias[cl];
#pragma unroll
            for (int e = 0; e < 4; ++e) {
                const int r = bm + wr * 64 + mi * 16 + (l >> 4) * 4 + e;
                const int gr = (r < S_TXT) ? (S_IMG + r) : (r - S_TXT);
                C[(size_t)gr * DIMC + cl] = acc[mi][ni][e] + bv;
            }
        }
}

// ---------------------------------------------------------------------------
// LayerNorm + RoPE on q,k rows of qkv; single-fp16 Q,K arrays [NH][S][128].
// ---------------------------------------------------------------------------
__global__ __launch_bounds__(256) void ln_rope_split(
    const float* __restrict__ qkv,
    const float* __restrict__ cost, const float* __restrict__ sint,
    _Float16* __restrict__ Qh, _Float16* __restrict__ Kh)
{
    const int wave = threadIdx.x >> 6;
    const int lane = threadIdx.x & 63;
    const int task = blockIdx.x * 4 + wave;
    const int s = task / 48;
    const int rem = task % 48;
    const int qk = rem / 24;
    const int h = rem % 24;

    const float* p = qkv + (size_t)s * QKV_N + qk * DIMC + h * HD;
    float2 x = *(const float2*)(p + lane * 2);

    float sum = x.x + x.y;
    float sq = x.x * x.x + x.y * x.y;
#pragma unroll
    for (int off = 1; off < 64; off <<= 1) {
        sum += __shfl_xor(sum, off, 64);
        sq  += __shfl_xor(sq, off, 64);
    }
    const float mu = sum * (1.0f / 128.0f);
    const float var = sq * (1.0f / 128.0f) - mu * mu;
    const float rstd = rsqrtf(var + 1e-5f);
    float y0 = (x.x - mu) * rstd;
    float y1 = (x.y - mu) * rstd;

    if (s >= S_TXT) {
        const int ip = s - S_TXT;
        const float c = cost[ip * 64 + lane];
        const float sn = sint[ip * 64 + lane];
        const float o0 = y0 * c - y1 * sn;
        const float o1 = y1 * c + y0 * sn;
        y0 = o0; y1 = o1;
    }

    const size_t off = ((size_t)h * S_TOT + s) * HD + lane * 2;
    f16x2 hv; hv.x = (_Float16)y0; hv.y = (_Float16)y1;
    *(f16x2*)((qk ? Kh : Qh) + off) = hv;
}

// ---------------------------------------------------------------------------
// V: qkv[s][2*3072 + h*128 + d] -> transposed single-fp16 Vt [NH][128][S]
// ---------------------------------------------------------------------------
__global__ __launch_bounds__(256) void v_split_transpose(
    const float* __restrict__ qkv, _Float16* __restrict__ Vth)
{
    __shared__ float T[64][132];
    const int h = blockIdx.y;
    const int s0 = blockIdx.x * 64;
    const int t = threadIdx.x;
    {
        const int sl = t >> 2, dp = (t & 3) * 32;
#pragma unroll
        for (int j = 0; j < 8; ++j) {
            float4 v = *(const float4*)(qkv + (size_t)(s0 + sl) * QKV_N + 2 * DIMC + h * HD + dp + j * 4);
            *(float4*)&T[sl][dp + j * 4] = v;
        }
    }
    __syncthreads();
    const int d = t >> 1, sh = (t & 1) * 32;
    f16x8 hv[4];
#pragma unroll
    for (int ss = 0; ss < 32; ++ss)
        hv[ss >> 3][ss & 7] = (_Float16)T[sh + ss][d];
    _Float16* bh = Vth + ((size_t)h * HD + d) * S_TOT + s0 + sh;
#pragma unroll
    for (int j = 0; j < 4; ++j)
        *(f16x8*)(bh + j * 8) = hv[j];
}

// ---------------------------------------------------------------------------
// Flash attention, single-fp16 MFMA (f32 softmax/accum).
// Block = (64 q-rows, head), 4 waves. Swapped scores S^T = K @ Q^T.
// Epilogue writes attn-out as hi/lo fp16 directly (feeds 3-term out-proj).
// ---------------------------------------------------------------------------
__global__ __launch_bounds__(256) void attn_mfma(
    const _Float16* __restrict__ Qg, const _Float16* __restrict__ Kg,
    const _Float16* __restrict__ Vg,
    _Float16* __restrict__ aoh, _Float16* __restrict__ aol)
{
    __shared__ __attribute__((aligned(16))) _Float16 Ksh[4][32][40];
    __shared__ __attribute__((aligned(16))) _Float16 Vsh[128][40];
    __shared__ __attribute__((aligned(16))) _Float16 Pah[4][16][40];

    const int h = blockIdx.y;
    const int q0 = blockIdx.x * 64;
    const int tid = threadIdx.x;
    const int w = tid >> 6, l = tid & 63;
    const int lr = l & 15, g = l >> 4, lk = g * 8;
    const float scale = 0.08838834764831845f;

    // Q fragments in registers (B-operand of swapped QK^T)
    const int qrow = q0 + w * 16 + lr;
    const _Float16* qb = Qg + ((size_t)h * S_TOT + qrow) * HD + lk;
    f16x8 qh[4];
#pragma unroll
    for (int db = 0; db < 4; ++db)
        qh[db] = *(const f16x8*)(qb + db * 32);

    f32x4 o[8] = {};
    float mrow = -3.0e38f, lrow = 0.0f;

    const int kr = tid >> 3, kdg = tid & 7, kdb = kdg >> 1, kco = (kdg & 1) * 16;
    const int vd = tid >> 1, vpt = (tid & 1) * 16;
    const _Float16* gK = Kg + ((size_t)h * S_TOT + kr) * HD + kdg * 16;
    const _Float16* gV = Vg + ((size_t)h * HD + vd) * S_TOT + vpt;

    uint4 rK0, rK1, rV0, rV1;
#define LOADKV(kv0) { \
    rK0 = *(const uint4*)(gK + (size_t)(kv0) * HD); rK1 = *(const uint4*)(gK + (size_t)(kv0) * HD + 8); \
    rV0 = *(const uint4*)(gV + (kv0)); rV1 = *(const uint4*)(gV + (kv0) + 8); }

    LOADKV(0);

    for (int kb = 0; kb < S_TOT / 32; ++kb) {
        __syncthreads();
        *(uint4*)&Ksh[kdb][kr][kco] = rK0; *(uint4*)&Ksh[kdb][kr][kco + 8] = rK1;
        *(uint4*)&Vsh[vd][vpt] = rV0; *(uint4*)&Vsh[vd][vpt + 8] = rV1;
        __syncthreads();
        if (kb + 1 < S_TOT / 32) LOADKV((kb + 1) * 32);

        // scores S^T (2 frags of 16kv x 16q)
        f32x4 sT[2] = {};
#pragma unroll
        for (int db = 0; db < 4; ++db)
#pragma unroll
            for (int mf = 0; mf < 2; ++mf) {
                f16x8 kf = *(const f16x8*)&Ksh[db][mf * 16 + lr][lk];
                sT[mf] = MFMA(kf, qh[db], sT[mf]);
            }

        // online softmax (stats per lane for q = lr)
        float sc_[2][4];
        float pm = -3.0e38f;
#pragma unroll
        for (int mf = 0; mf < 2; ++mf)
#pragma unroll
            for (int e = 0; e < 4; ++e) {
                const float s = sT[mf][e] * scale;
                sc_[mf][e] = s;
                pm = fmaxf(pm, s);
            }
        pm = fmaxf(pm, __shfl_xor(pm, 16, 64));
        pm = fmaxf(pm, __shfl_xor(pm, 32, 64));
        const float mnew = fmaxf(mrow, pm);
        float rs = 0.0f;
        float ex_[2][4];
#pragma unroll
        for (int mf = 0; mf < 2; ++mf)
#pragma unroll
            for (int e = 0; e < 4; ++e) {
                const float pv = __expf(sc_[mf][e] - mnew);
                ex_[mf][e] = pv;
                rs += pv;
            }
        rs += __shfl_xor(rs, 16, 64);
        rs += __shfl_xor(rs, 32, 64);
        const float alpha = __expf(mrow - mnew);
        lrow = lrow * alpha + rs;
        mrow = mnew;

        // rescale O (O rows are q = g*4+e; alpha held at lane == q)
        const float a0 = __shfl(alpha, g * 4 + 0, 64);
        const float a1 = __shfl(alpha, g * 4 + 1, 64);
        const float a2 = __shfl(alpha, g * 4 + 2, 64);
        const float a3 = __shfl(alpha, g * 4 + 3, 64);
#pragma unroll
        for (int df = 0; df < 8; ++df) {
            o[df][0] *= a0; o[df][1] *= a1; o[df][2] *= a2; o[df][3] *= a3;
        }

        // publish P (fp16) into per-wave LDS slice, layout [q][kv]
#pragma unroll
        for (int mf = 0; mf < 2; ++mf) {
            const int kvb = mf * 16 + g * 4;
            f16x2 t0; t0.x = (_Float16)ex_[mf][0]; t0.y = (_Float16)ex_[mf][1];
            f16x2 t1; t1.x = (_Float16)ex_[mf][2]; t1.y = (_Float16)ex_[mf][3];
            *(f16x2*)&Pah[w][lr][kvb] = t0;
            *(f16x2*)&Pah[w][lr][kvb + 2] = t1;
        }

        // PV: O(16q x 128d) += P(16x32) @ V(32x128)
        f16x8 pa = *(const f16x8*)&Pah[w][lr][lk];
#pragma unroll
        for (int df = 0; df < 8; ++df) {
            f16x8 vf = *(const f16x8*)&Vsh[df * 16 + lr][lk];
            o[df] = MFMA(pa, vf, o[df]);
        }
    }
#undef LOADKV

    const float inv = 1.0f / lrow;
    const float b0 = __shfl(inv, g * 4 + 0, 64);
    const float b1 = __shfl(inv, g * 4 + 1, 64);
    const float b2 = __shfl(inv, g * 4 + 2, 64);
    const float b3 = __shfl(inv, g * 4 + 3, 64);
    const float bb[4] = {b0, b1, b2, b3};
#pragma unroll
    for (int df = 0; df < 8; ++df)
#pragma unroll
        for (int e = 0; e < 4; ++e) {
            const int r = q0 + w * 16 + g * 4 + e;
            const size_t idx = (size_t)r * DIMC + h * HD + df * 16 + lr;
            _Float16 hh, ll;
            split1(o[df][e] * bb[e], hh, ll);
            aoh[idx] = hh;
            aol[idx] = ll;
        }
}

// ---------------------------------------------------------------------------
extern "C" void kernel_launch(void* const* d_in, const int* in_sizes, int n_in,
                              void* d_out, int out_size, void* d_ws, size_t ws_size,
                              hipStream_t stream)
{
    const float* hid  = (const float*)d_in[0];
    const float* enc  = (const float*)d_in[1];
    const float* cost = (const float*)d_in[2];
    const float* sint = (const float*)d_in[3];
    const float* Wqkv = (const float*)d_in[4];
    const float* bqkv = (const float*)d_in[5];
    const float* Wout = (const float*)d_in[6];
    const float* bout = (const float*)d_in[7];
    float* out = (float*)d_out;

    char* ws = (char*)d_ws;
    float*    qkv  = (float*)(ws + 0);                  // 84.93 MB, dead after phase 2
    _Float16* aoh  = (_Float16*)(ws + 0);               // phase 3+, over qkv
    _Float16* aol  = (_Float16*)(ws + 14155776);
    _Float16* xh   = (_Float16*)(ws + 84934656);        // phase 1
    _Float16* Qh   = (_Float16*)(ws + 84934656);        // phase 2+, over xh
    _Float16* Kh   = (_Float16*)(ws + 99090432);
    _Float16* Wth  = (_Float16*)(ws + 113246208);       // phase 1
    _Float16* Vth  = (_Float16*)(ws + 113246208);       // phase 2+, over Wth
    _Float16* Wtl  = (_Float16*)(ws + 132120576);       // phase 1
    _Float16* W2h  = (_Float16*)(ws + 132120576);       // phase 4, over Wtl
    _Float16* W2l  = (_Float16*)(ws + 150994944);       // end 169.87 MB

    split_x<<<S_TOT, 256, 0, stream>>>(enc, hid, xh);
    for (int c = 0; c < 3; ++c) {
        transpose_split_w<<<dim3(48, 48), 256, 0, stream>>>(Wqkv + c * DIMC, QKV_N, Wth, Wtl);
        gemm_f16_2t<<<dim3(24, 18), 256, 0, stream>>>(
            xh, Wth, Wtl, bqkv + c * DIMC, qkv + c * DIMC, QKV_N);
    }
    ln_rope_split<<<(S_TOT * 48) / 4, 256, 0, stream>>>(qkv, cost, sint, Qh, Kh);
    v_split_transpose<<<dim3(36, 24), 256, 0, stream>>>(qkv, Vth);
    attn_mfma<<<dim3(36, 24), 256, 0, stream>>>(Qh, Kh, Vth, aoh, aol);
    transpose_split_w<<<dim3(48, 48), 256, 0, stream>>>(Wout, DIMC, W2h, W2l);
    gemm_f16_3t<<<dim3(24, 18), 256, 0, stream>>>(aoh, aol, W2h, W2l, bout, out);
}

// Round 4
// 546.862 us; speedup vs baseline: 8.2096x; 1.4031x over previous
//
#include <hip/hip_runtime.h>

#define DIMC 3072
#define NH 24
#define HD 128
#define QKV_N 9216
#define S_TXT 256
#define S_IMG 2048
#define S_TOT 2304

typedef _Float16 f16x8 __attribute__((ext_vector_type(8)));
typedef _Float16 f16x4 __attribute__((ext_vector_type(4)));
typedef _Float16 f16x2 __attribute__((ext_vector_type(2)));
typedef float f32x4 __attribute__((ext_vector_type(4)));

#define MFMA(A, B, C) __builtin_amdgcn_mfma_f32_16x16x32_f16(A, B, C, 0, 0, 0)

// scale(1/sqrt(128)) * log2(e): scores computed directly in log2 domain
#define QSCALE (0.08838834764831845f * 1.4426950408889634f)

// ---------------------------------------------------------------------------
// concat(enc,hid) -> fp16 (hi only)
// ---------------------------------------------------------------------------
__global__ __launch_bounds__(256) void split_x(
    const float* __restrict__ enc, const float* __restrict__ hid,
    _Float16* __restrict__ xh)
{
    const int s = blockIdx.x;
    const float* src = (s < S_TXT) ? enc + (size_t)s * DIMC
                                   : hid + (size_t)(s - S_TXT) * DIMC;
    const int t = threadIdx.x;
#pragma unroll
    for (int it = 0; it < 3; ++it) {
        const int i = (it * 256 + t) * 4;
        float4 v = *(const float4*)(src + i);
        f16x4 hv;
        hv.x = (_Float16)v.x; hv.y = (_Float16)v.y;
        hv.z = (_Float16)v.z; hv.w = (_Float16)v.w;
        *(f16x4*)(xh + (size_t)s * DIMC + i) = hv;
    }
}

// ---------------------------------------------------------------------------
// W [3072 k][ldw] f32 -> Wt [n][3072 k] fp16 (hi only)
// ---------------------------------------------------------------------------
__global__ __launch_bounds__(256) void transpose_w_hi(
    const float* __restrict__ W, const int ldw, _Float16* __restrict__ Th)
{
    __shared__ float T[64][68];
    const int n0 = blockIdx.x * 64, k0 = blockIdx.y * 64;
    const int t = threadIdx.x;
    {
        const int r = t >> 2, c4 = (t & 3) * 16;
#pragma unroll
        for (int j = 0; j < 4; ++j) {
            float4 v = *(const float4*)(W + (size_t)(k0 + r) * ldw + n0 + c4 + j * 4);
            *(float4*)&T[r][c4 + j * 4] = v;
        }
    }
    __syncthreads();
    const int nr = t >> 2, kp = (t & 3) * 16;
    f16x8 hv0, hv1;
#pragma unroll
    for (int j = 0; j < 8; ++j) hv0[j] = (_Float16)T[kp + j][nr];
#pragma unroll
    for (int j = 0; j < 8; ++j) hv1[j] = (_Float16)T[kp + 8 + j][nr];
    _Float16* dh = Th + (size_t)(n0 + nr) * DIMC + k0 + kp;
    *(f16x8*)(dh) = hv0; *(f16x8*)(dh + 8) = hv1;
}

// ---------------------------------------------------------------------------
// Single-term fp16 GEMM: C[M][ldc] = A @ B^T + bias.
// A [m][3072 k] fp16, B [n][3072 k] fp16. 128x128 tile, BK=32, 4 waves.
// ---------------------------------------------------------------------------
template <int REMAP>
__global__ __launch_bounds__(256) void gemm_f16_1t(
    const _Float16* __restrict__ Ah, const _Float16* __restrict__ Bh,
    const float* __restrict__ bias, float* __restrict__ C, const int ldc)
{
    __shared__ __attribute__((aligned(16))) _Float16 Ash[128][40];
    __shared__ __attribute__((aligned(16))) _Float16 Bsh[128][40];

    const int tid = threadIdx.x;
    const int l = tid & 63, w = tid >> 6;
    const int wr = w >> 1, wc = w & 1;
    const int lr = l & 15, lk = (l >> 4) * 8;
    const int bm = blockIdx.y * 128, bn = blockIdx.x * 128;
    const int srow = tid >> 1, shalf = (tid & 1) * 16;

    const _Float16* gAh = Ah + (size_t)(bm + srow) * DIMC + shalf;
    const _Float16* gBh = Bh + (size_t)(bn + srow) * DIMC + shalf;

    f32x4 acc[4][4] = {};
    uint4 rA0, rA1, rB0, rB1;

#define LOADT(k0) { \
    rA0 = *(const uint4*)(gAh + (k0));     rA1 = *(const uint4*)(gAh + (k0) + 8); \
    rB0 = *(const uint4*)(gBh + (k0));     rB1 = *(const uint4*)(gBh + (k0) + 8); }

    LOADT(0);
    for (int k0 = 0; k0 < DIMC; k0 += 32) {
        __syncthreads();
        *(uint4*)&Ash[srow][shalf] = rA0; *(uint4*)&Ash[srow][shalf + 8] = rA1;
        *(uint4*)&Bsh[srow][shalf] = rB0; *(uint4*)&Bsh[srow][shalf + 8] = rB1;
        __syncthreads();
        if (k0 + 32 < DIMC) LOADT(k0 + 32);

        f16x8 bhf[4];
#pragma unroll
        for (int ni = 0; ni < 4; ++ni)
            bhf[ni] = *(const f16x8*)&Bsh[wc * 64 + ni * 16 + lr][lk];
#pragma unroll
        for (int mi = 0; mi < 4; ++mi) {
            f16x8 ahf = *(const f16x8*)&Ash[wr * 64 + mi * 16 + lr][lk];
#pragma unroll
            for (int ni = 0; ni < 4; ++ni)
                acc[mi][ni] = MFMA(ahf, bhf[ni], acc[mi][ni]);
        }
    }
#undef LOADT

#pragma unroll
    for (int mi = 0; mi < 4; ++mi)
#pragma unroll
        for (int ni = 0; ni < 4; ++ni) {
            const int cl = bn + wc * 64 + ni * 16 + lr;
            const float bv = bias[cl];
#pragma unroll
            for (int e = 0; e < 4; ++e) {
                const int r = bm + wr * 64 + mi * 16 + (l >> 4) * 4 + e;
                if (REMAP) {
                    const int gr = (r < S_TXT) ? (S_IMG + r) : (r - S_TXT);
                    C[(size_t)gr * DIMC + cl] = acc[mi][ni][e] + bv;
                } else {
                    C[(size_t)r * ldc + cl] = acc[mi][ni][e] + bv;
                }
            }
        }
}

// ---------------------------------------------------------------------------
// LayerNorm + RoPE; Q is pre-scaled by scale*log2(e). fp16 out [NH][S][128].
// ---------------------------------------------------------------------------
__global__ __launch_bounds__(256) void ln_rope_split(
    const float* __restrict__ qkv,
    const float* __restrict__ cost, const float* __restrict__ sint,
    _Float16* __restrict__ Qh, _Float16* __restrict__ Kh)
{
    const int wave = threadIdx.x >> 6;
    const int lane = threadIdx.x & 63;
    const int task = blockIdx.x * 4 + wave;
    const int s = task / 48;
    const int rem = task % 48;
    const int qk = rem / 24;
    const int h = rem % 24;

    const float* p = qkv + (size_t)s * QKV_N + qk * DIMC + h * HD;
    float2 x = *(const float2*)(p + lane * 2);

    float sum = x.x + x.y;
    float sq = x.x * x.x + x.y * x.y;
#pragma unroll
    for (int off = 1; off < 64; off <<= 1) {
        sum += __shfl_xor(sum, off, 64);
        sq  += __shfl_xor(sq, off, 64);
    }
    const float mu = sum * (1.0f / 128.0f);
    const float var = sq * (1.0f / 128.0f) - mu * mu;
    const float rstd = rsqrtf(var + 1e-5f);
    float y0 = (x.x - mu) * rstd;
    float y1 = (x.y - mu) * rstd;

    if (s >= S_TXT) {
        const int ip = s - S_TXT;
        const float c = cost[ip * 64 + lane];
        const float sn = sint[ip * 64 + lane];
        const float o0 = y0 * c - y1 * sn;
        const float o1 = y1 * c + y0 * sn;
        y0 = o0; y1 = o1;
    }
    if (qk == 0) { y0 *= QSCALE; y1 *= QSCALE; }

    const size_t off = ((size_t)h * S_TOT + s) * HD + lane * 2;
    f16x2 hv; hv.x = (_Float16)y0; hv.y = (_Float16)y1;
    *(f16x2*)((qk ? Kh : Qh) + off) = hv;
}

// ---------------------------------------------------------------------------
// V: qkv[s][2*3072 + h*128 + d] -> transposed fp16 Vt [NH][128][S]
// ---------------------------------------------------------------------------
__global__ __launch_bounds__(256) void v_split_transpose(
    const float* __restrict__ qkv, _Float16* __restrict__ Vth)
{
    __shared__ float T[64][132];
    const int h = blockIdx.y;
    const int s0 = blockIdx.x * 64;
    const int t = threadIdx.x;
    {
        const int sl = t >> 2, dp = (t & 3) * 32;
#pragma unroll
        for (int j = 0; j < 8; ++j) {
            float4 v = *(const float4*)(qkv + (size_t)(s0 + sl) * QKV_N + 2 * DIMC + h * HD + dp + j * 4);
            *(float4*)&T[sl][dp + j * 4] = v;
        }
    }
    __syncthreads();
    const int d = t >> 1, sh = (t & 1) * 32;
    f16x8 hv[4];
#pragma unroll
    for (int ss = 0; ss < 32; ++ss)
        hv[ss >> 3][ss & 7] = (_Float16)T[sh + ss][d];
    _Float16* bh = Vth + ((size_t)h * HD + d) * S_TOT + s0 + sh;
#pragma unroll
    for (int j = 0; j < 4; ++j)
        *(f16x8*)(bh + j * 8) = hv[j];
}

// ---------------------------------------------------------------------------
// Flash attention, fp16 MFMA, log2-domain softmax, defer-max (THR=11).
// Block = (64 q, head), 4 waves x 16 q. KVBLK=64. Swapped scores K@Q^T.
// ---------------------------------------------------------------------------
__global__ __launch_bounds__(256) void attn_mfma(
    const _Float16* __restrict__ Qg, const _Float16* __restrict__ Kg,
    const _Float16* __restrict__ Vg, _Float16* __restrict__ aoh)
{
    __shared__ __attribute__((aligned(16))) _Float16 Ksh[4][64][40]; // [d-blk][kv][d' 32+8]
    __shared__ __attribute__((aligned(16))) _Float16 Vsh[128][80];   // [d][kv 64+16]
    __shared__ __attribute__((aligned(16))) _Float16 Pah[4][16][80]; // per-wave [q][kv 64+16]

    const int h = blockIdx.y;
    const int q0 = blockIdx.x * 64;
    const int tid = threadIdx.x;
    const int w = tid >> 6, l = tid & 63;
    const int lr = l & 15, g = l >> 4, lk = g * 8;

    // Q fragments (pre-scaled by QSCALE in ln_rope_split)
    const int qrow = q0 + w * 16 + lr;
    const _Float16* qb = Qg + ((size_t)h * S_TOT + qrow) * HD + lk;
    f16x8 qh[4];
#pragma unroll
    for (int db = 0; db < 4; ++db)
        qh[db] = *(const f16x8*)(qb + db * 32);

    f32x4 o[8] = {};
    float mrow = -3.0e38f, lrow = 0.0f;

    // staging: K: thread -> kv=tid>>2, d-blk=tid&3 (32 d = 4x16B)
    //          V: thread -> d=tid>>1, kv-half=(tid&1)*32
    const int kkv = tid >> 2, kdb = tid & 3;
    const int vd = tid >> 1, vkh = (tid & 1) * 32;
    const _Float16* gK = Kg + ((size_t)h * S_TOT + kkv) * HD + kdb * 32;
    const _Float16* gV = Vg + ((size_t)h * HD + vd) * S_TOT + vkh;

    uint4 rK0, rK1, rK2, rK3, rV0, rV1, rV2, rV3;
#define LOADKV(kv0) { \
    rK0 = *(const uint4*)(gK + (size_t)(kv0) * HD);      rK1 = *(const uint4*)(gK + (size_t)(kv0) * HD + 8); \
    rK2 = *(const uint4*)(gK + (size_t)(kv0) * HD + 16); rK3 = *(const uint4*)(gK + (size_t)(kv0) * HD + 24); \
    rV0 = *(const uint4*)(gV + (kv0));      rV1 = *(const uint4*)(gV + (kv0) + 8); \
    rV2 = *(const uint4*)(gV + (kv0) + 16); rV3 = *(const uint4*)(gV + (kv0) + 24); }

    LOADKV(0);

    for (int kb = 0; kb < S_TOT / 64; ++kb) {
        __syncthreads();
        *(uint4*)&Ksh[kdb][kkv][0]  = rK0; *(uint4*)&Ksh[kdb][kkv][8]  = rK1;
        *(uint4*)&Ksh[kdb][kkv][16] = rK2; *(uint4*)&Ksh[kdb][kkv][24] = rK3;
        *(uint4*)&Vsh[vd][vkh]      = rV0; *(uint4*)&Vsh[vd][vkh + 8]  = rV1;
        *(uint4*)&Vsh[vd][vkh + 16] = rV2; *(uint4*)&Vsh[vd][vkh + 24] = rV3;
        __syncthreads();
        if (kb + 1 < S_TOT / 64) LOADKV((kb + 1) * 64);

        // scores S^T: 4 frags (16 kv x 16 q), log2 domain
        f32x4 sT[4] = {};
        __builtin_amdgcn_s_setprio(1);
#pragma unroll
        for (int db = 0; db < 4; ++db)
#pragma unroll
            for (int mf = 0; mf < 4; ++mf) {
                f16x8 kf = *(const f16x8*)&Ksh[db][mf * 16 + lr][lk];
                sT[mf] = MFMA(kf, qh[db], sT[mf]);
            }
        __builtin_amdgcn_s_setprio(0);

        // per-lane max over this tile's 16 kv values (q = lr)
        float pm = -3.0e38f;
#pragma unroll
        for (int mf = 0; mf < 4; ++mf)
#pragma unroll
            for (int e = 0; e < 4; ++e)
                pm = fmaxf(pm, sT[mf][e]);
        pm = fmaxf(pm, __shfl_xor(pm, 16, 64));
        pm = fmaxf(pm, __shfl_xor(pm, 32, 64));

        // defer-max: rescale only when max grew by > 11 (log2 domain)
        if (__any(pm > mrow + 11.0f)) {
            const float mnew = fmaxf(mrow, pm);
            const float alpha = exp2f(mrow - mnew);
            lrow *= alpha;
            mrow = mnew;
            const float a0 = __shfl(alpha, g * 4 + 0, 64);
            const float a1 = __shfl(alpha, g * 4 + 1, 64);
            const float a2 = __shfl(alpha, g * 4 + 2, 64);
            const float a3 = __shfl(alpha, g * 4 + 3, 64);
#pragma unroll
            for (int df = 0; df < 8; ++df) {
                o[df][0] *= a0; o[df][1] *= a1; o[df][2] *= a2; o[df][3] *= a3;
            }
        }

        float rs = 0.0f;
        float ex_[4][4];
#pragma unroll
        for (int mf = 0; mf < 4; ++mf)
#pragma unroll
            for (int e = 0; e < 4; ++e) {
                const float pv = exp2f(sT[mf][e] - mrow);
                ex_[mf][e] = pv;
                rs += pv;
            }
        rs += __shfl_xor(rs, 16, 64);
        rs += __shfl_xor(rs, 32, 64);
        lrow += rs;

        // publish P into per-wave LDS slice, layout [q][kv]
#pragma unroll
        for (int mf = 0; mf < 4; ++mf) {
            const int kvb = mf * 16 + g * 4;
            f16x2 t0; t0.x = (_Float16)ex_[mf][0]; t0.y = (_Float16)ex_[mf][1];
            f16x2 t1; t1.x = (_Float16)ex_[mf][2]; t1.y = (_Float16)ex_[mf][3];
            *(f16x2*)&Pah[w][lr][kvb] = t0;
            *(f16x2*)&Pah[w][lr][kvb + 2] = t1;
        }

        // PV: O(16q x 128d) += P(16x64) @ V(64x128)
        f16x8 pa0 = *(const f16x8*)&Pah[w][lr][lk];
        f16x8 pa1 = *(const f16x8*)&Pah[w][lr][32 + lk];
        __builtin_amdgcn_s_setprio(1);
#pragma unroll
        for (int df = 0; df < 8; ++df) {
            f16x8 vf0 = *(const f16x8*)&Vsh[df * 16 + lr][lk];
            f16x8 vf1 = *(const f16x8*)&Vsh[df * 16 + lr][32 + lk];
            o[df] = MFMA(pa0, vf0, o[df]);
            o[df] = MFMA(pa1, vf1, o[df]);
        }
        __builtin_amdgcn_s_setprio(0);
    }
#undef LOADKV

    const float inv = 1.0f / lrow;
    const float b0 = __shfl(inv, g * 4 + 0, 64);
    const float b1 = __shfl(inv, g * 4 + 1, 64);
    const float b2 = __shfl(inv, g * 4 + 2, 64);
    const float b3 = __shfl(inv, g * 4 + 3, 64);
    const float bb[4] = {b0, b1, b2, b3};
#pragma unroll
    for (int df = 0; df < 8; ++df)
#pragma unroll
        for (int e = 0; e < 4; ++e) {
            const int r = q0 + w * 16 + g * 4 + e;
            aoh[(size_t)r * DIMC + h * HD + df * 16 + lr] = (_Float16)(o[df][e] * bb[e]);
        }
}

// ---------------------------------------------------------------------------
extern "C" void kernel_launch(void* const* d_in, const int* in_sizes, int n_in,
                              void* d_out, int out_size, void* d_ws, size_t ws_size,
                              hipStream_t stream)
{
    const float* hid  = (const float*)d_in[0];
    const float* enc  = (const float*)d_in[1];
    const float* cost = (const float*)d_in[2];
    const float* sint = (const float*)d_in[3];
    const float* Wqkv = (const float*)d_in[4];
    const float* bqkv = (const float*)d_in[5];
    const float* Wout = (const float*)d_in[6];
    const float* bout = (const float*)d_in[7];
    float* out = (float*)d_out;

    char* ws = (char*)d_ws;
    float*    qkv  = (float*)(ws + 0);            // 84.93 MB; dead after v_transpose
    _Float16* aoh  = (_Float16*)(ws + 0);         // attn out, over qkv
    _Float16* xh   = (_Float16*)(ws + 84934656);  // then Qh over it
    _Float16* Qh   = (_Float16*)(ws + 84934656);
    _Float16* Kh   = (_Float16*)(ws + 99090432);
    _Float16* Wth  = (_Float16*)(ws + 113246208); // full Wqkv^T hi, 56.6 MB (dead after gemm)
    _Float16* Vth  = (_Float16*)(ws + 113246208); // over Wth
    _Float16* W2h  = (_Float16*)(ws + 132120576); // 18.87 MB (after Wth dead)

    split_x<<<S_TOT, 256, 0, stream>>>(enc, hid, xh);
    transpose_w_hi<<<dim3(144, 48), 256, 0, stream>>>(Wqkv, QKV_N, Wth);
    gemm_f16_1t<0><<<dim3(72, 18), 256, 0, stream>>>(xh, Wth, bqkv, qkv, QKV_N);
    transpose_w_hi<<<dim3(48, 48), 256, 0, stream>>>(Wout, DIMC, W2h);
    ln_rope_split<<<(S_TOT * 48) / 4, 256, 0, stream>>>(qkv, cost, sint, Qh, Kh);
    v_split_transpose<<<dim3(36, 24), 256, 0, stream>>>(qkv, Vth);
    attn_mfma<<<dim3(36, 24), 256, 0, stream>>>(Qh, Kh, Vth, aoh);
    gemm_f16_1t<1><<<dim3(24, 18), 256, 0, stream>>>(aoh, W2h, bout, out, DIMC);
}

// Round 5
// 491.661 us; speedup vs baseline: 9.1313x; 1.1123x over previous
//
#include <hip/hip_runtime.h>

#define DIMC 3072
#define NH 24
#define HD 128
#define QKV_N 9216
#define S_TXT 256
#define S_IMG 2048
#define S_TOT 2304

typedef _Float16 f16x8 __attribute__((ext_vector_type(8)));
typedef _Float16 f16x4 __attribute__((ext_vector_type(4)));
typedef _Float16 f16x2 __attribute__((ext_vector_type(2)));
typedef float f32x4 __attribute__((ext_vector_type(4)));

#define MFMA(A, B, C) __builtin_amdgcn_mfma_f32_16x16x32_f16(A, B, C, 0, 0, 0)

// scale(1/sqrt(128)) * log2(e): scores computed directly in log2 domain
#define QSCALE (0.08838834764831845f * 1.4426950408889634f)

// direct global->LDS async copy, 16B per lane; lds base must be wave-uniform
__device__ __forceinline__ void gl2lds16(const _Float16* g, _Float16* l) {
    __builtin_amdgcn_global_load_lds(
        (const __attribute__((address_space(1))) unsigned int*)g,
        (__attribute__((address_space(3))) unsigned int*)l,
        16, 0, 0);
}

// ---------------------------------------------------------------------------
// concat(enc,hid) -> fp16 (hi only)
// ---------------------------------------------------------------------------
__global__ __launch_bounds__(256) void split_x(
    const float* __restrict__ enc, const float* __restrict__ hid,
    _Float16* __restrict__ xh)
{
    const int s = blockIdx.x;
    const float* src = (s < S_TXT) ? enc + (size_t)s * DIMC
                                   : hid + (size_t)(s - S_TXT) * DIMC;
    const int t = threadIdx.x;
#pragma unroll
    for (int it = 0; it < 3; ++it) {
        const int i = (it * 256 + t) * 4;
        float4 v = *(const float4*)(src + i);
        f16x4 hv;
        hv.x = (_Float16)v.x; hv.y = (_Float16)v.y;
        hv.z = (_Float16)v.z; hv.w = (_Float16)v.w;
        *(f16x4*)(xh + (size_t)s * DIMC + i) = hv;
    }
}

// ---------------------------------------------------------------------------
// W [3072 k][ldw] f32 -> Wt [n][3072 k] fp16 (hi only)
// ---------------------------------------------------------------------------
__global__ __launch_bounds__(256) void transpose_w_hi(
    const float* __restrict__ W, const int ldw, _Float16* __restrict__ Th)
{
    __shared__ float T[64][68];
    const int n0 = blockIdx.x * 64, k0 = blockIdx.y * 64;
    const int t = threadIdx.x;
    {
        const int r = t >> 2, c4 = (t & 3) * 16;
#pragma unroll
        for (int j = 0; j < 4; ++j) {
            float4 v = *(const float4*)(W + (size_t)(k0 + r) * ldw + n0 + c4 + j * 4);
            *(float4*)&T[r][c4 + j * 4] = v;
        }
    }
    __syncthreads();
    const int nr = t >> 2, kp = (t & 3) * 16;
    f16x8 hv0, hv1;
#pragma unroll
    for (int j = 0; j < 8; ++j) hv0[j] = (_Float16)T[kp + j][nr];
#pragma unroll
    for (int j = 0; j < 8; ++j) hv1[j] = (_Float16)T[kp + 8 + j][nr];
    _Float16* dh = Th + (size_t)(n0 + nr) * DIMC + k0 + kp;
    *(f16x8*)(dh) = hv0; *(f16x8*)(dh + 8) = hv1;
}

// ---------------------------------------------------------------------------
// m97-structure fp16 GEMM: C = A @ B^T + bias.
// A [m][3072 k] fp16, B [n][3072 k] fp16. 128x128 tile, BK=32, 4 waves 2x2.
// Staging: global_load_lds width=16, linear LDS [row][32k], 2-barrier loop.
// Block remap: m-block fastest (co-resident blocks share B panels in L2).
// ---------------------------------------------------------------------------
template <int REMAP>
__global__ __launch_bounds__(256) void gemm_f16_lds(
    const _Float16* __restrict__ Ah, const _Float16* __restrict__ Bh,
    const float* __restrict__ bias, float* __restrict__ C,
    const int nblk_m, const int ldc)
{
    __shared__ __attribute__((aligned(16))) _Float16 Ash[128 * 32];
    __shared__ __attribute__((aligned(16))) _Float16 Bsh[128 * 32];

    const int bid = blockIdx.x;
    const int bm = (bid % nblk_m) * 128;
    const int bn = (bid / nblk_m) * 128;

    const int tid = threadIdx.x;
    const int l = tid & 63, w = tid >> 6;
    const int wr = w >> 1, wc = w & 1;
    const int lr = l & 15, g = l >> 4, lk = g * 8;

    // staging: wave w covers tile rows [w*32, w*32+32) in two 16-row chunks.
    // lane i -> row chunk_row0 + i/4, halfwords (i&3)*8  (= linear lane*16B)
    const int srow = w * 32 + (l >> 2);
    const int skp  = (l & 3) * 8;
    const _Float16* gA0 = Ah + (size_t)(bm + srow) * DIMC + skp;
    const _Float16* gA1 = Ah + (size_t)(bm + srow + 16) * DIMC + skp;
    const _Float16* gB0 = Bh + (size_t)(bn + srow) * DIMC + skp;
    const _Float16* gB1 = Bh + (size_t)(bn + srow + 16) * DIMC + skp;
    _Float16* lA0 = &Ash[(w * 32) * 32];
    _Float16* lA1 = &Ash[(w * 32 + 16) * 32];
    _Float16* lB0 = &Bsh[(w * 32) * 32];
    _Float16* lB1 = &Bsh[(w * 32 + 16) * 32];

    f32x4 acc[4][4] = {};

    for (int k0 = 0; k0 < DIMC; k0 += 32) {
        gl2lds16(gA0 + k0, lA0);
        gl2lds16(gA1 + k0, lA1);
        gl2lds16(gB0 + k0, lB0);
        gl2lds16(gB1 + k0, lB1);
        __syncthreads();   // vmcnt(0) drain + barrier (compiler-inserted wait)

        f16x8 bhf[4];
#pragma unroll
        for (int ni = 0; ni < 4; ++ni)
            bhf[ni] = *(const f16x8*)&Bsh[(wc * 64 + ni * 16 + lr) * 32 + lk];
#pragma unroll
        for (int mi = 0; mi < 4; ++mi) {
            f16x8 ahf = *(const f16x8*)&Ash[(wr * 64 + mi * 16 + lr) * 32 + lk];
#pragma unroll
            for (int ni = 0; ni < 4; ++ni)
                acc[mi][ni] = MFMA(ahf, bhf[ni], acc[mi][ni]);
        }
        __syncthreads();   // all reads done before next stage overwrites
    }

#pragma unroll
    for (int mi = 0; mi < 4; ++mi)
#pragma unroll
        for (int ni = 0; ni < 4; ++ni) {
            const int cl = bn + wc * 64 + ni * 16 + lr;
            const float bv = bias[cl];
#pragma unroll
            for (int e = 0; e < 4; ++e) {
                const int r = bm + wr * 64 + mi * 16 + g * 4 + e;
                if (REMAP) {
                    const int gr = (r < S_TXT) ? (S_IMG + r) : (r - S_TXT);
                    C[(size_t)gr * DIMC + cl] = acc[mi][ni][e] + bv;
                } else {
                    C[(size_t)r * ldc + cl] = acc[mi][ni][e] + bv;
                }
            }
        }
}

// ---------------------------------------------------------------------------
// LayerNorm + RoPE; Q is pre-scaled by scale*log2(e). fp16 out [NH][S][128].
// ---------------------------------------------------------------------------
__global__ __launch_bounds__(256) void ln_rope_split(
    const float* __restrict__ qkv,
    const float* __restrict__ cost, const float* __restrict__ sint,
    _Float16* __restrict__ Qh, _Float16* __restrict__ Kh)
{
    const int wave = threadIdx.x >> 6;
    const int lane = threadIdx.x & 63;
    const int task = blockIdx.x * 4 + wave;
    const int s = task / 48;
    const int rem = task % 48;
    const int qk = rem / 24;
    const int h = rem % 24;

    const float* p = qkv + (size_t)s * QKV_N + qk * DIMC + h * HD;
    float2 x = *(const float2*)(p + lane * 2);

    float sum = x.x + x.y;
    float sq = x.x * x.x + x.y * x.y;
#pragma unroll
    for (int off = 1; off < 64; off <<= 1) {
        sum += __shfl_xor(sum, off, 64);
        sq  += __shfl_xor(sq, off, 64);
    }
    const float mu = sum * (1.0f / 128.0f);
    const float var = sq * (1.0f / 128.0f) - mu * mu;
    const float rstd = rsqrtf(var + 1e-5f);
    float y0 = (x.x - mu) * rstd;
    float y1 = (x.y - mu) * rstd;

    if (s >= S_TXT) {
        const int ip = s - S_TXT;
        const float c = cost[ip * 64 + lane];
        const float sn = sint[ip * 64 + lane];
        const float o0 = y0 * c - y1 * sn;
        const float o1 = y1 * c + y0 * sn;
        y0 = o0; y1 = o1;
    }
    if (qk == 0) { y0 *= QSCALE; y1 *= QSCALE; }

    const size_t off = ((size_t)h * S_TOT + s) * HD + lane * 2;
    f16x2 hv; hv.x = (_Float16)y0; hv.y = (_Float16)y1;
    *(f16x2*)((qk ? Kh : Qh) + off) = hv;
}

// ---------------------------------------------------------------------------
// V: qkv[s][2*3072 + h*128 + d] -> transposed fp16 Vt [NH][128][S]
// ---------------------------------------------------------------------------
__global__ __launch_bounds__(256) void v_split_transpose(
    const float* __restrict__ qkv, _Float16* __restrict__ Vth)
{
    __shared__ float T[64][132];
    const int h = blockIdx.y;
    const int s0 = blockIdx.x * 64;
    const int t = threadIdx.x;
    {
        const int sl = t >> 2, dp = (t & 3) * 32;
#pragma unroll
        for (int j = 0; j < 8; ++j) {
            float4 v = *(const float4*)(qkv + (size_t)(s0 + sl) * QKV_N + 2 * DIMC + h * HD + dp + j * 4);
            *(float4*)&T[sl][dp + j * 4] = v;
        }
    }
    __syncthreads();
    const int d = t >> 1, sh = (t & 1) * 32;
    f16x8 hv[4];
#pragma unroll
    for (int ss = 0; ss < 32; ++ss)
        hv[ss >> 3][ss & 7] = (_Float16)T[sh + ss][d];
    _Float16* bh = Vth + ((size_t)h * HD + d) * S_TOT + s0 + sh;
#pragma unroll
    for (int j = 0; j < 4; ++j)
        *(f16x8*)(bh + j * 8) = hv[j];
}

// ---------------------------------------------------------------------------
// Flash attention, fp16 MFMA, log2-domain softmax, defer-max (THR=11).
// Block = (64 q, head), 4 waves x 16 q. KVBLK=64. Swapped scores K@Q^T.
// ---------------------------------------------------------------------------
__global__ __launch_bounds__(256) void attn_mfma(
    const _Float16* __restrict__ Qg, const _Float16* __restrict__ Kg,
    const _Float16* __restrict__ Vg, _Float16* __restrict__ aoh)
{
    __shared__ __attribute__((aligned(16))) _Float16 Ksh[4][64][40]; // [d-blk][kv][d' 32+8]
    __shared__ __attribute__((aligned(16))) _Float16 Vsh[128][80];   // [d][kv 64+16]
    __shared__ __attribute__((aligned(16))) _Float16 Pah[4][16][80]; // per-wave [q][kv 64+16]

    const int h = blockIdx.y;
    const int q0 = blockIdx.x * 64;
    const int tid = threadIdx.x;
    const int w = tid >> 6, l = tid & 63;
    const int lr = l & 15, g = l >> 4, lk = g * 8;

    // Q fragments (pre-scaled by QSCALE in ln_rope_split)
    const int qrow = q0 + w * 16 + lr;
    const _Float16* qb = Qg + ((size_t)h * S_TOT + qrow) * HD + lk;
    f16x8 qh[4];
#pragma unroll
    for (int db = 0; db < 4; ++db)
        qh[db] = *(const f16x8*)(qb + db * 32);

    f32x4 o[8] = {};
    float mrow = -3.0e38f, lrow = 0.0f;

    const int kkv = tid >> 2, kdb = tid & 3;
    const int vd = tid >> 1, vkh = (tid & 1) * 32;
    const _Float16* gK = Kg + ((size_t)h * S_TOT + kkv) * HD + kdb * 32;
    const _Float16* gV = Vg + ((size_t)h * HD + vd) * S_TOT + vkh;

    uint4 rK0, rK1, rK2, rK3, rV0, rV1, rV2, rV3;
#define LOADKV(kv0) { \
    rK0 = *(const uint4*)(gK + (size_t)(kv0) * HD);      rK1 = *(const uint4*)(gK + (size_t)(kv0) * HD + 8); \
    rK2 = *(const uint4*)(gK + (size_t)(kv0) * HD + 16); rK3 = *(const uint4*)(gK + (size_t)(kv0) * HD + 24); \
    rV0 = *(const uint4*)(gV + (kv0));      rV1 = *(const uint4*)(gV + (kv0) + 8); \
    rV2 = *(const uint4*)(gV + (kv0) + 16); rV3 = *(const uint4*)(gV + (kv0) + 24); }

    LOADKV(0);

    for (int kb = 0; kb < S_TOT / 64; ++kb) {
        __syncthreads();
        *(uint4*)&Ksh[kdb][kkv][0]  = rK0; *(uint4*)&Ksh[kdb][kkv][8]  = rK1;
        *(uint4*)&Ksh[kdb][kkv][16] = rK2; *(uint4*)&Ksh[kdb][kkv][24] = rK3;
        *(uint4*)&Vsh[vd][vkh]      = rV0; *(uint4*)&Vsh[vd][vkh + 8]  = rV1;
        *(uint4*)&Vsh[vd][vkh + 16] = rV2; *(uint4*)&Vsh[vd][vkh + 24] = rV3;
        __syncthreads();
        if (kb + 1 < S_TOT / 64) LOADKV((kb + 1) * 64);

        // scores S^T: 4 frags (16 kv x 16 q), log2 domain
        f32x4 sT[4] = {};
        __builtin_amdgcn_s_setprio(1);
#pragma unroll
        for (int db = 0; db < 4; ++db)
#pragma unroll
            for (int mf = 0; mf < 4; ++mf) {
                f16x8 kf = *(const f16x8*)&Ksh[db][mf * 16 + lr][lk];
                sT[mf] = MFMA(kf, qh[db], sT[mf]);
            }
        __builtin_amdgcn_s_setprio(0);

        // per-lane max over this tile's 16 kv values (q = lr)
        float pm = -3.0e38f;
#pragma unroll
        for (int mf = 0; mf < 4; ++mf)
#pragma unroll
            for (int e = 0; e < 4; ++e)
                pm = fmaxf(pm, sT[mf][e]);
        pm = fmaxf(pm, __shfl_xor(pm, 16, 64));
        pm = fmaxf(pm, __shfl_xor(pm, 32, 64));

        // defer-max: rescale only when max grew by > 11 (log2 domain)
        if (__any(pm > mrow + 11.0f)) {
            const float mnew = fmaxf(mrow, pm);
            const float alpha = exp2f(mrow - mnew);
            lrow *= alpha;
            mrow = mnew;
            const float a0 = __shfl(alpha, g * 4 + 0, 64);
            const float a1 = __shfl(alpha, g * 4 + 1, 64);
            const float a2 = __shfl(alpha, g * 4 + 2, 64);
            const float a3 = __shfl(alpha, g * 4 + 3, 64);
#pragma unroll
            for (int df = 0; df < 8; ++df) {
                o[df][0] *= a0; o[df][1] *= a1; o[df][2] *= a2; o[df][3] *= a3;
            }
        }

        float rs = 0.0f;
        float ex_[4][4];
#pragma unroll
        for (int mf = 0; mf < 4; ++mf)
#pragma unroll
            for (int e = 0; e < 4; ++e) {
                const float pv = exp2f(sT[mf][e] - mrow);
                ex_[mf][e] = pv;
                rs += pv;
            }
        rs += __shfl_xor(rs, 16, 64);
        rs += __shfl_xor(rs, 32, 64);
        lrow += rs;

        // publish P into per-wave LDS slice, layout [q][kv]
#pragma unroll
        for (int mf = 0; mf < 4; ++mf) {
            const int kvb = mf * 16 + g * 4;
            f16x2 t0; t0.x = (_Float16)ex_[mf][0]; t0.y = (_Float16)ex_[mf][1];
            f16x2 t1; t1.x = (_Float16)ex_[mf][2]; t1.y = (_Float16)ex_[mf][3];
            *(f16x2*)&Pah[w][lr][kvb] = t0;
            *(f16x2*)&Pah[w][lr][kvb + 2] = t1;
        }

        // PV: O(16q x 128d) += P(16x64) @ V(64x128)
        f16x8 pa0 = *(const f16x8*)&Pah[w][lr][lk];
        f16x8 pa1 = *(const f16x8*)&Pah[w][lr][32 + lk];
        __builtin_amdgcn_s_setprio(1);
#pragma unroll
        for (int df = 0; df < 8; ++df) {
            f16x8 vf0 = *(const f16x8*)&Vsh[df * 16 + lr][lk];
            f16x8 vf1 = *(const f16x8*)&Vsh[df * 16 + lr][32 + lk];
            o[df] = MFMA(pa0, vf0, o[df]);
            o[df] = MFMA(pa1, vf1, o[df]);
        }
        __builtin_amdgcn_s_setprio(0);
    }
#undef LOADKV

    const float inv = 1.0f / lrow;
    const float b0 = __shfl(inv, g * 4 + 0, 64);
    const float b1 = __shfl(inv, g * 4 + 1, 64);
    const float b2 = __shfl(inv, g * 4 + 2, 64);
    const float b3 = __shfl(inv, g * 4 + 3, 64);
    const float bb[4] = {b0, b1, b2, b3};
#pragma unroll
    for (int df = 0; df < 8; ++df)
#pragma unroll
        for (int e = 0; e < 4; ++e) {
            const int r = q0 + w * 16 + g * 4 + e;
            aoh[(size_t)r * DIMC + h * HD + df * 16 + lr] = (_Float16)(o[df][e] * bb[e]);
        }
}

// ---------------------------------------------------------------------------
extern "C" void kernel_launch(void* const* d_in, const int* in_sizes, int n_in,
                              void* d_out, int out_size, void* d_ws, size_t ws_size,
                              hipStream_t stream)
{
    const float* hid  = (const float*)d_in[0];
    const float* enc  = (const float*)d_in[1];
    const float* cost = (const float*)d_in[2];
    const float* sint = (const float*)d_in[3];
    const float* Wqkv = (const float*)d_in[4];
    const float* bqkv = (const float*)d_in[5];
    const float* Wout = (const float*)d_in[6];
    const float* bout = (const float*)d_in[7];
    float* out = (float*)d_out;

    char* ws = (char*)d_ws;
    float*    qkv  = (float*)(ws + 0);            // 84.93 MB; dead after v_transpose
    _Float16* aoh  = (_Float16*)(ws + 0);         // attn out, over qkv
    _Float16* xh   = (_Float16*)(ws + 84934656);  // then Qh over it
    _Float16* Qh   = (_Float16*)(ws + 84934656);
    _Float16* Kh   = (_Float16*)(ws + 99090432);
    _Float16* Wth  = (_Float16*)(ws + 113246208); // full Wqkv^T hi, 56.6 MB (dead after gemm)
    _Float16* Vth  = (_Float16*)(ws + 113246208); // over Wth
    _Float16* W2h  = (_Float16*)(ws + 132120576); // 18.87 MB (after Wth dead)

    split_x<<<S_TOT, 256, 0, stream>>>(enc, hid, xh);
    transpose_w_hi<<<dim3(144, 48), 256, 0, stream>>>(Wqkv, QKV_N, Wth);
    gemm_f16_lds<0><<<18 * 72, 256, 0, stream>>>(xh, Wth, bqkv, qkv, 18, QKV_N);
    transpose_w_hi<<<dim3(48, 48), 256, 0, stream>>>(Wout, DIMC, W2h);
    ln_rope_split<<<(S_TOT * 48) / 4, 256, 0, stream>>>(qkv, cost, sint, Qh, Kh);
    v_split_transpose<<<dim3(36, 24), 256, 0, stream>>>(qkv, Vth);
    attn_mfma<<<dim3(36, 24), 256, 0, stream>>>(Qh, Kh, Vth, aoh);
    gemm_f16_lds<1><<<18 * 24, 256, 0, stream>>>(aoh, W2h, bout, out, 18, DIMC);
}

// Round 6
// 477.391 us; speedup vs baseline: 9.4043x; 1.0299x over previous
//
#include <hip/hip_runtime.h>

#define DIMC 3072
#define NH 24
#define HD 128
#define QKV_N 9216
#define S_TXT 256
#define S_IMG 2048
#define S_TOT 2304

typedef _Float16 f16x8 __attribute__((ext_vector_type(8)));
typedef _Float16 f16x4 __attribute__((ext_vector_type(4)));
typedef _Float16 f16x2 __attribute__((ext_vector_type(2)));
typedef float f32x4 __attribute__((ext_vector_type(4)));

#define MFMA(A, B, C) __builtin_amdgcn_mfma_f32_16x16x32_f16(A, B, C, 0, 0, 0)

// scale(1/sqrt(128)) * log2(e): scores computed directly in log2 domain
#define QSCALE (0.08838834764831845f * 1.4426950408889634f)

// direct global->LDS async copy, 16B per lane; lds base must be wave-uniform
__device__ __forceinline__ void gl2lds16(const _Float16* g, _Float16* l) {
    __builtin_amdgcn_global_load_lds(
        (const __attribute__((address_space(1))) unsigned int*)g,
        (__attribute__((address_space(3))) unsigned int*)l,
        16, 0, 0);
}

// ---------------------------------------------------------------------------
// concat(enc,hid) -> fp16 (hi only)
// ---------------------------------------------------------------------------
__global__ __launch_bounds__(256) void split_x(
    const float* __restrict__ enc, const float* __restrict__ hid,
    _Float16* __restrict__ xh)
{
    const int s = blockIdx.x;
    const float* src = (s < S_TXT) ? enc + (size_t)s * DIMC
                                   : hid + (size_t)(s - S_TXT) * DIMC;
    const int t = threadIdx.x;
#pragma unroll
    for (int it = 0; it < 3; ++it) {
        const int i = (it * 256 + t) * 4;
        float4 v = *(const float4*)(src + i);
        f16x4 hv;
        hv.x = (_Float16)v.x; hv.y = (_Float16)v.y;
        hv.z = (_Float16)v.z; hv.w = (_Float16)v.w;
        *(f16x4*)(xh + (size_t)s * DIMC + i) = hv;
    }
}

// ---------------------------------------------------------------------------
// W [3072 k][ldw] f32 -> Wt [n][3072 k] fp16 (hi only)
// ---------------------------------------------------------------------------
__global__ __launch_bounds__(256) void transpose_w_hi(
    const float* __restrict__ W, const int ldw, _Float16* __restrict__ Th)
{
    __shared__ float T[64][68];
    const int n0 = blockIdx.x * 64, k0 = blockIdx.y * 64;
    const int t = threadIdx.x;
    {
        const int r = t >> 2, c4 = (t & 3) * 16;
#pragma unroll
        for (int j = 0; j < 4; ++j) {
            float4 v = *(const float4*)(W + (size_t)(k0 + r) * ldw + n0 + c4 + j * 4);
            *(float4*)&T[r][c4 + j * 4] = v;
        }
    }
    __syncthreads();
    const int nr = t >> 2, kp = (t & 3) * 16;
    f16x8 hv0, hv1;
#pragma unroll
    for (int j = 0; j < 8; ++j) hv0[j] = (_Float16)T[kp + j][nr];
#pragma unroll
    for (int j = 0; j < 8; ++j) hv1[j] = (_Float16)T[kp + 8 + j][nr];
    _Float16* dh = Th + (size_t)(n0 + nr) * DIMC + k0 + kp;
    *(f16x8*)(dh) = hv0; *(f16x8*)(dh + 8) = hv1;
}

// ---------------------------------------------------------------------------
// m97-structure fp16 GEMM: C = A @ B^T + bias.
// 128x128 tile, BK=32, 4 waves 2x2, global_load_lds width=16.
// T1: XCD-chunked blockIdx swizzle (grid % 8 == 0 required).
// T2: both-sides LDS slot-XOR (linear LDS dest, pre-swizzled global source,
//     swizzled ds_read slot): slot' = slot ^ ((row>>1)&3) -> 2 lanes/bank.
// ---------------------------------------------------------------------------
template <int REMAP>
__global__ __launch_bounds__(256) void gemm_f16_lds(
    const _Float16* __restrict__ Ah, const _Float16* __restrict__ Bh,
    const float* __restrict__ bias, float* __restrict__ C,
    const int nblk_m, const int ldc)
{
    __shared__ __attribute__((aligned(16))) _Float16 Ash[128 * 32];
    __shared__ __attribute__((aligned(16))) _Float16 Bsh[128 * 32];

    // T1: physical XCD of block b is b%8; give each XCD a contiguous chunk
    const int cpx = (int)gridDim.x >> 3;
    const int wgid = (blockIdx.x & 7) * cpx + (blockIdx.x >> 3);
    const int bm = (wgid % nblk_m) * 128;
    const int bn = (wgid / nblk_m) * 128;

    const int tid = threadIdx.x;
    const int l = tid & 63, w = tid >> 6;
    const int wr = w >> 1, wc = w & 1;
    const int lr = l & 15, g = l >> 4;

    // staging: wave w covers tile rows [w*32, w*32+32) in two 16-row chunks.
    // LDS dest is linear (lane*16B); SOURCE k-slot is pre-XOR'd by row (T2).
    const int srow0 = w * 32 + (l >> 2);          // rows for chunk 0
    const int srow1 = srow0 + 16;                 // rows for chunk 1
    const int skp0 = (((l & 3) ^ ((srow0 >> 1) & 3)) * 8);
    const int skp1 = (((l & 3) ^ ((srow1 >> 1) & 3)) * 8);
    const _Float16* gA0 = Ah + (size_t)(bm + srow0) * DIMC + skp0;
    const _Float16* gA1 = Ah + (size_t)(bm + srow1) * DIMC + skp1;
    const _Float16* gB0 = Bh + (size_t)(bn + srow0) * DIMC + skp0;
    const _Float16* gB1 = Bh + (size_t)(bn + srow1) * DIMC + skp1;
    _Float16* lA0 = &Ash[(w * 32) * 32];
    _Float16* lA1 = &Ash[(w * 32 + 16) * 32];
    _Float16* lB0 = &Bsh[(w * 32) * 32];
    _Float16* lB1 = &Bsh[(w * 32 + 16) * 32];

    // swizzled read offsets (frag row -> byte slot)
    int aoff[4], boff[4];
#pragma unroll
    for (int i = 0; i < 4; ++i) {
        const int ra = wr * 64 + i * 16 + lr;
        const int rb = wc * 64 + i * 16 + lr;
        aoff[i] = ra * 32 + ((g ^ ((ra >> 1) & 3)) * 8);
        boff[i] = rb * 32 + ((g ^ ((rb >> 1) & 3)) * 8);
    }

    f32x4 acc[4][4] = {};

    for (int k0 = 0; k0 < DIMC; k0 += 32) {
        gl2lds16(gA0 + k0, lA0);
        gl2lds16(gA1 + k0, lA1);
        gl2lds16(gB0 + k0, lB0);
        gl2lds16(gB1 + k0, lB1);
        __syncthreads();

        f16x8 bhf[4];
#pragma unroll
        for (int ni = 0; ni < 4; ++ni)
            bhf[ni] = *(const f16x8*)&Bsh[boff[ni]];
#pragma unroll
        for (int mi = 0; mi < 4; ++mi) {
            f16x8 ahf = *(const f16x8*)&Ash[aoff[mi]];
#pragma unroll
            for (int ni = 0; ni < 4; ++ni)
                acc[mi][ni] = MFMA(ahf, bhf[ni], acc[mi][ni]);
        }
        __syncthreads();
    }

#pragma unroll
    for (int mi = 0; mi < 4; ++mi)
#pragma unroll
        for (int ni = 0; ni < 4; ++ni) {
            const int cl = bn + wc * 64 + ni * 16 + lr;
            const float bv = bias[cl];
#pragma unroll
            for (int e = 0; e < 4; ++e) {
                const int r = bm + wr * 64 + mi * 16 + g * 4 + e;
                if (REMAP) {
                    const int gr = (r < S_TXT) ? (S_IMG + r) : (r - S_TXT);
                    C[(size_t)gr * DIMC + cl] = acc[mi][ni][e] + bv;
                } else {
                    C[(size_t)r * ldc + cl] = acc[mi][ni][e] + bv;
                }
            }
        }
}

// ---------------------------------------------------------------------------
// LayerNorm + RoPE; Q is pre-scaled by scale*log2(e). fp16 out [NH][S][128].
// ---------------------------------------------------------------------------
__global__ __launch_bounds__(256) void ln_rope_split(
    const float* __restrict__ qkv,
    const float* __restrict__ cost, const float* __restrict__ sint,
    _Float16* __restrict__ Qh, _Float16* __restrict__ Kh)
{
    const int wave = threadIdx.x >> 6;
    const int lane = threadIdx.x & 63;
    const int task = blockIdx.x * 4 + wave;
    const int s = task / 48;
    const int rem = task % 48;
    const int qk = rem / 24;
    const int h = rem % 24;

    const float* p = qkv + (size_t)s * QKV_N + qk * DIMC + h * HD;
    float2 x = *(const float2*)(p + lane * 2);

    float sum = x.x + x.y;
    float sq = x.x * x.x + x.y * x.y;
#pragma unroll
    for (int off = 1; off < 64; off <<= 1) {
        sum += __shfl_xor(sum, off, 64);
        sq  += __shfl_xor(sq, off, 64);
    }
    const float mu = sum * (1.0f / 128.0f);
    const float var = sq * (1.0f / 128.0f) - mu * mu;
    const float rstd = rsqrtf(var + 1e-5f);
    float y0 = (x.x - mu) * rstd;
    float y1 = (x.y - mu) * rstd;

    if (s >= S_TXT) {
        const int ip = s - S_TXT;
        const float c = cost[ip * 64 + lane];
        const float sn = sint[ip * 64 + lane];
        const float o0 = y0 * c - y1 * sn;
        const float o1 = y1 * c + y0 * sn;
        y0 = o0; y1 = o1;
    }
    if (qk == 0) { y0 *= QSCALE; y1 *= QSCALE; }

    const size_t off = ((size_t)h * S_TOT + s) * HD + lane * 2;
    f16x2 hv; hv.x = (_Float16)y0; hv.y = (_Float16)y1;
    *(f16x2*)((qk ? Kh : Qh) + off) = hv;
}

// ---------------------------------------------------------------------------
// V: qkv[s][2*3072 + h*128 + d] -> transposed fp16 Vt [NH][128][S]
// ---------------------------------------------------------------------------
__global__ __launch_bounds__(256) void v_split_transpose(
    const float* __restrict__ qkv, _Float16* __restrict__ Vth)
{
    __shared__ float T[64][132];
    const int h = blockIdx.y;
    const int s0 = blockIdx.x * 64;
    const int t = threadIdx.x;
    {
        const int sl = t >> 2, dp = (t & 3) * 32;
#pragma unroll
        for (int j = 0; j < 8; ++j) {
            float4 v = *(const float4*)(qkv + (size_t)(s0 + sl) * QKV_N + 2 * DIMC + h * HD + dp + j * 4);
            *(float4*)&T[sl][dp + j * 4] = v;
        }
    }
    __syncthreads();
    const int d = t >> 1, sh = (t & 1) * 32;
    f16x8 hv[4];
#pragma unroll
    for (int ss = 0; ss < 32; ++ss)
        hv[ss >> 3][ss & 7] = (_Float16)T[sh + ss][d];
    _Float16* bh = Vth + ((size_t)h * HD + d) * S_TOT + s0 + sh;
#pragma unroll
    for (int j = 0; j < 4; ++j)
        *(f16x8*)(bh + j * 8) = hv[j];
}

// ---------------------------------------------------------------------------
// Flash attention, fp16 MFMA, log2-domain softmax, defer-max (THR=11).
// Block = (64 q, head), 4 waves x 16 q. KVBLK=64. Swapped scores K@Q^T.
// ---------------------------------------------------------------------------
__global__ __launch_bounds__(256) void attn_mfma(
    const _Float16* __restrict__ Qg, const _Float16* __restrict__ Kg,
    const _Float16* __restrict__ Vg, _Float16* __restrict__ aoh)
{
    __shared__ __attribute__((aligned(16))) _Float16 Ksh[4][64][40]; // [d-blk][kv][d' 32+8]
    __shared__ __attribute__((aligned(16))) _Float16 Vsh[128][80];   // [d][kv 64+16]
    __shared__ __attribute__((aligned(16))) _Float16 Pah[4][16][80]; // per-wave [q][kv 64+16]

    const int h = blockIdx.y;
    const int q0 = blockIdx.x * 64;
    const int tid = threadIdx.x;
    const int w = tid >> 6, l = tid & 63;
    const int lr = l & 15, g = l >> 4, lk = g * 8;

    // Q fragments (pre-scaled by QSCALE in ln_rope_split)
    const int qrow = q0 + w * 16 + lr;
    const _Float16* qb = Qg + ((size_t)h * S_TOT + qrow) * HD + lk;
    f16x8 qh[4];
#pragma unroll
    for (int db = 0; db < 4; ++db)
        qh[db] = *(const f16x8*)(qb + db * 32);

    f32x4 o[8] = {};
    float mrow = -3.0e38f, lrow = 0.0f;

    const int kkv = tid >> 2, kdb = tid & 3;
    const int vd = tid >> 1, vkh = (tid & 1) * 32;
    const _Float16* gK = Kg + ((size_t)h * S_TOT + kkv) * HD + kdb * 32;
    const _Float16* gV = Vg + ((size_t)h * HD + vd) * S_TOT + vkh;

    uint4 rK0, rK1, rK2, rK3, rV0, rV1, rV2, rV3;
#define LOADKV(kv0) { \
    rK0 = *(const uint4*)(gK + (size_t)(kv0) * HD);      rK1 = *(const uint4*)(gK + (size_t)(kv0) * HD + 8); \
    rK2 = *(const uint4*)(gK + (size_t)(kv0) * HD + 16); rK3 = *(const uint4*)(gK + (size_t)(kv0) * HD + 24); \
    rV0 = *(const uint4*)(gV + (kv0));      rV1 = *(const uint4*)(gV + (kv0) + 8); \
    rV2 = *(const uint4*)(gV + (kv0) + 16); rV3 = *(const uint4*)(gV + (kv0) + 24); }

    LOADKV(0);

    for (int kb = 0; kb < S_TOT / 64; ++kb) {
        __syncthreads();
        *(uint4*)&Ksh[kdb][kkv][0]  = rK0; *(uint4*)&Ksh[kdb][kkv][8]  = rK1;
        *(uint4*)&Ksh[kdb][kkv][16] = rK2; *(uint4*)&Ksh[kdb][kkv][24] = rK3;
        *(uint4*)&Vsh[vd][vkh]      = rV0; *(uint4*)&Vsh[vd][vkh + 8]  = rV1;
        *(uint4*)&Vsh[vd][vkh + 16] = rV2; *(uint4*)&Vsh[vd][vkh + 24] = rV3;
        __syncthreads();
        if (kb + 1 < S_TOT / 64) LOADKV((kb + 1) * 64);

        // scores S^T: 4 frags (16 kv x 16 q), log2 domain
        f32x4 sT[4] = {};
        __builtin_amdgcn_s_setprio(1);
#pragma unroll
        for (int db = 0; db < 4; ++db)
#pragma unroll
            for (int mf = 0; mf < 4; ++mf) {
                f16x8 kf = *(const f16x8*)&Ksh[db][mf * 16 + lr][lk];
                sT[mf] = MFMA(kf, qh[db], sT[mf]);
            }
        __builtin_amdgcn_s_setprio(0);

        // per-lane max over this tile's 16 kv values (q = lr)
        float pm = -3.0e38f;
#pragma unroll
        for (int mf = 0; mf < 4; ++mf)
#pragma unroll
            for (int e = 0; e < 4; ++e)
                pm = fmaxf(pm, sT[mf][e]);
        pm = fmaxf(pm, __shfl_xor(pm, 16, 64));
        pm = fmaxf(pm, __shfl_xor(pm, 32, 64));

        // defer-max: rescale only when max grew by > 11 (log2 domain)
        if (__any(pm > mrow + 11.0f)) {
            const float mnew = fmaxf(mrow, pm);
            const float alpha = exp2f(mrow - mnew);
            lrow *= alpha;
            mrow = mnew;
            const float a0 = __shfl(alpha, g * 4 + 0, 64);
            const float a1 = __shfl(alpha, g * 4 + 1, 64);
            const float a2 = __shfl(alpha, g * 4 + 2, 64);
            const float a3 = __shfl(alpha, g * 4 + 3, 64);
#pragma unroll
            for (int df = 0; df < 8; ++df) {
                o[df][0] *= a0; o[df][1] *= a1; o[df][2] *= a2; o[df][3] *= a3;
            }
        }

        float rs = 0.0f;
        float ex_[4][4];
#pragma unroll
        for (int mf = 0; mf < 4; ++mf)
#pragma unroll
            for (int e = 0; e < 4; ++e) {
                const float pv = exp2f(sT[mf][e] - mrow);
                ex_[mf][e] = pv;
                rs += pv;
            }
        rs += __shfl_xor(rs, 16, 64);
        rs += __shfl_xor(rs, 32, 64);
        lrow += rs;

        // publish P into per-wave LDS slice, layout [q][kv]
#pragma unroll
        for (int mf = 0; mf < 4; ++mf) {
            const int kvb = mf * 16 + g * 4;
            f16x2 t0; t0.x = (_Float16)ex_[mf][0]; t0.y = (_Float16)ex_[mf][1];
            f16x2 t1; t1.x = (_Float16)ex_[mf][2]; t1.y = (_Float16)ex_[mf][3];
            *(f16x2*)&Pah[w][lr][kvb] = t0;
            *(f16x2*)&Pah[w][lr][kvb + 2] = t1;
        }

        // PV: O(16q x 128d) += P(16x64) @ V(64x128)
        f16x8 pa0 = *(const f16x8*)&Pah[w][lr][lk];
        f16x8 pa1 = *(const f16x8*)&Pah[w][lr][32 + lk];
        __builtin_amdgcn_s_setprio(1);
#pragma unroll
        for (int df = 0; df < 8; ++df) {
            f16x8 vf0 = *(const f16x8*)&Vsh[df * 16 + lr][lk];
            f16x8 vf1 = *(const f16x8*)&Vsh[df * 16 + lr][32 + lk];
            o[df] = MFMA(pa0, vf0, o[df]);
            o[df] = MFMA(pa1, vf1, o[df]);
        }
        __builtin_amdgcn_s_setprio(0);
    }
#undef LOADKV

    const float inv = 1.0f / lrow;
    const float b0 = __shfl(inv, g * 4 + 0, 64);
    const float b1 = __shfl(inv, g * 4 + 1, 64);
    const float b2 = __shfl(inv, g * 4 + 2, 64);
    const float b3 = __shfl(inv, g * 4 + 3, 64);
    const float bb[4] = {b0, b1, b2, b3};
#pragma unroll
    for (int df = 0; df < 8; ++df)
#pragma unroll
        for (int e = 0; e < 4; ++e) {
            const int r = q0 + w * 16 + g * 4 + e;
            aoh[(size_t)r * DIMC + h * HD + df * 16 + lr] = (_Float16)(o[df][e] * bb[e]);
        }
}

// ---------------------------------------------------------------------------
extern "C" void kernel_launch(void* const* d_in, const int* in_sizes, int n_in,
                              void* d_out, int out_size, void* d_ws, size_t ws_size,
                              hipStream_t stream)
{
    const float* hid  = (const float*)d_in[0];
    const float* enc  = (const float*)d_in[1];
    const float* cost = (const float*)d_in[2];
    const float* sint = (const float*)d_in[3];
    const float* Wqkv = (const float*)d_in[4];
    const float* bqkv = (const float*)d_in[5];
    const float* Wout = (const float*)d_in[6];
    const float* bout = (const float*)d_in[7];
    float* out = (float*)d_out;

    char* ws = (char*)d_ws;
    float*    qkv  = (float*)(ws + 0);            // 84.93 MB; dead after v_transpose
    _Float16* aoh  = (_Float16*)(ws + 0);         // attn out, over qkv
    _Float16* xh   = (_Float16*)(ws + 84934656);  // then Qh over it
    _Float16* Qh   = (_Float16*)(ws + 84934656);
    _Float16* Kh   = (_Float16*)(ws + 99090432);
    _Float16* Wth  = (_Float16*)(ws + 113246208); // full Wqkv^T hi, 56.6 MB (dead after gemm)
    _Float16* Vth  = (_Float16*)(ws + 113246208); // over Wth
    _Float16* W2h  = (_Float16*)(ws + 132120576); // 18.87 MB (after Wth dead)

    split_x<<<S_TOT, 256, 0, stream>>>(enc, hid, xh);
    transpose_w_hi<<<dim3(144, 48), 256, 0, stream>>>(Wqkv, QKV_N, Wth);
    gemm_f16_lds<0><<<18 * 72, 256, 0, stream>>>(xh, Wth, bqkv, qkv, 18, QKV_N);
    transpose_w_hi<<<dim3(48, 48), 256, 0, stream>>>(Wout, DIMC, W2h);
    ln_rope_split<<<(S_TOT * 48) / 4, 256, 0, stream>>>(qkv, cost, sint, Qh, Kh);
    v_split_transpose<<<dim3(36, 24), 256, 0, stream>>>(qkv, Vth);
    attn_mfma<<<dim3(36, 24), 256, 0, stream>>>(Qh, Kh, Vth, aoh);
    gemm_f16_lds<1><<<18 * 24, 256, 0, stream>>>(aoh, W2h, bout, out, 18, DIMC);
}

// Round 7
// 464.079 us; speedup vs baseline: 9.6740x; 1.0287x over previous
//
#include <hip/hip_runtime.h>

#define DIMC 3072
#define NH 24
#define HD 128
#define QKV_N 9216
#define S_TXT 256
#define S_IMG 2048
#define S_TOT 2304

typedef _Float16 f16x8 __attribute__((ext_vector_type(8)));
typedef _Float16 f16x4 __attribute__((ext_vector_type(4)));
typedef _Float16 f16x2 __attribute__((ext_vector_type(2)));
typedef float f32x4 __attribute__((ext_vector_type(4)));

#define MFMA(A, B, C) __builtin_amdgcn_mfma_f32_16x16x32_f16(A, B, C, 0, 0, 0)

// scale(1/sqrt(128)) * log2(e): scores computed directly in log2 domain
#define QSCALE (0.08838834764831845f * 1.4426950408889634f)

// direct global->LDS async copy, 16B per lane; lds base must be wave-uniform
__device__ __forceinline__ void gl2lds16(const _Float16* g, _Float16* l) {
    __builtin_amdgcn_global_load_lds(
        (const __attribute__((address_space(1))) unsigned int*)g,
        (__attribute__((address_space(3))) unsigned int*)l,
        16, 0, 0);
}

// ---------------------------------------------------------------------------
// concat(enc,hid) -> fp16 (hi only)
// ---------------------------------------------------------------------------
__global__ __launch_bounds__(256) void split_x(
    const float* __restrict__ enc, const float* __restrict__ hid,
    _Float16* __restrict__ xh)
{
    const int s = blockIdx.x;
    const float* src = (s < S_TXT) ? enc + (size_t)s * DIMC
                                   : hid + (size_t)(s - S_TXT) * DIMC;
    const int t = threadIdx.x;
#pragma unroll
    for (int it = 0; it < 3; ++it) {
        const int i = (it * 256 + t) * 4;
        float4 v = *(const float4*)(src + i);
        f16x4 hv;
        hv.x = (_Float16)v.x; hv.y = (_Float16)v.y;
        hv.z = (_Float16)v.z; hv.w = (_Float16)v.w;
        *(f16x4*)(xh + (size_t)s * DIMC + i) = hv;
    }
}

// ---------------------------------------------------------------------------
// W [3072 k][ldw] f32 -> Wt [n][3072 k] fp16 (hi only)
// ---------------------------------------------------------------------------
__global__ __launch_bounds__(256) void transpose_w_hi(
    const float* __restrict__ W, const int ldw, _Float16* __restrict__ Th)
{
    __shared__ float T[64][68];
    const int n0 = blockIdx.x * 64, k0 = blockIdx.y * 64;
    const int t = threadIdx.x;
    {
        const int r = t >> 2, c4 = (t & 3) * 16;
#pragma unroll
        for (int j = 0; j < 4; ++j) {
            float4 v = *(const float4*)(W + (size_t)(k0 + r) * ldw + n0 + c4 + j * 4);
            *(float4*)&T[r][c4 + j * 4] = v;
        }
    }
    __syncthreads();
    const int nr = t >> 2, kp = (t & 3) * 16;
    f16x8 hv0, hv1;
#pragma unroll
    for (int j = 0; j < 8; ++j) hv0[j] = (_Float16)T[kp + j][nr];
#pragma unroll
    for (int j = 0; j < 8; ++j) hv1[j] = (_Float16)T[kp + 8 + j][nr];
    _Float16* dh = Th + (size_t)(n0 + nr) * DIMC + k0 + kp;
    *(f16x8*)(dh) = hv0; *(f16x8*)(dh + 8) = hv1;
}

// ---------------------------------------------------------------------------
// m97-structure fp16 GEMM: C = A @ B^T + bias.
// 128x128 tile, BK=32, 4 waves 2x2, global_load_lds width=16.
// T1 XCD-chunked swizzle + T2 both-sides LDS slot-XOR (0 conflicts, R6).
// ---------------------------------------------------------------------------
template <int REMAP>
__global__ __launch_bounds__(256) void gemm_f16_lds(
    const _Float16* __restrict__ Ah, const _Float16* __restrict__ Bh,
    const float* __restrict__ bias, float* __restrict__ C,
    const int nblk_m, const int ldc)
{
    __shared__ __attribute__((aligned(16))) _Float16 Ash[128 * 32];
    __shared__ __attribute__((aligned(16))) _Float16 Bsh[128 * 32];

    const int cpx = (int)gridDim.x >> 3;
    const int wgid = (blockIdx.x & 7) * cpx + (blockIdx.x >> 3);
    const int bm = (wgid % nblk_m) * 128;
    const int bn = (wgid / nblk_m) * 128;

    const int tid = threadIdx.x;
    const int l = tid & 63, w = tid >> 6;
    const int wr = w >> 1, wc = w & 1;
    const int lr = l & 15, g = l >> 4;

    const int srow0 = w * 32 + (l >> 2);
    const int srow1 = srow0 + 16;
    const int skp0 = (((l & 3) ^ ((srow0 >> 1) & 3)) * 8);
    const int skp1 = (((l & 3) ^ ((srow1 >> 1) & 3)) * 8);
    const _Float16* gA0 = Ah + (size_t)(bm + srow0) * DIMC + skp0;
    const _Float16* gA1 = Ah + (size_t)(bm + srow1) * DIMC + skp1;
    const _Float16* gB0 = Bh + (size_t)(bn + srow0) * DIMC + skp0;
    const _Float16* gB1 = Bh + (size_t)(bn + srow1) * DIMC + skp1;
    _Float16* lA0 = &Ash[(w * 32) * 32];
    _Float16* lA1 = &Ash[(w * 32 + 16) * 32];
    _Float16* lB0 = &Bsh[(w * 32) * 32];
    _Float16* lB1 = &Bsh[(w * 32 + 16) * 32];

    int aoff[4], boff[4];
#pragma unroll
    for (int i = 0; i < 4; ++i) {
        const int ra = wr * 64 + i * 16 + lr;
        const int rb = wc * 64 + i * 16 + lr;
        aoff[i] = ra * 32 + ((g ^ ((ra >> 1) & 3)) * 8);
        boff[i] = rb * 32 + ((g ^ ((rb >> 1) & 3)) * 8);
    }

    f32x4 acc[4][4] = {};

    for (int k0 = 0; k0 < DIMC; k0 += 32) {
        gl2lds16(gA0 + k0, lA0);
        gl2lds16(gA1 + k0, lA1);
        gl2lds16(gB0 + k0, lB0);
        gl2lds16(gB1 + k0, lB1);
        __syncthreads();

        f16x8 bhf[4];
#pragma unroll
        for (int ni = 0; ni < 4; ++ni)
            bhf[ni] = *(const f16x8*)&Bsh[boff[ni]];
#pragma unroll
        for (int mi = 0; mi < 4; ++mi) {
            f16x8 ahf = *(const f16x8*)&Ash[aoff[mi]];
#pragma unroll
            for (int ni = 0; ni < 4; ++ni)
                acc[mi][ni] = MFMA(ahf, bhf[ni], acc[mi][ni]);
        }
        __syncthreads();
    }

#pragma unroll
    for (int mi = 0; mi < 4; ++mi)
#pragma unroll
        for (int ni = 0; ni < 4; ++ni) {
            const int cl = bn + wc * 64 + ni * 16 + lr;
            const float bv = bias[cl];
#pragma unroll
            for (int e = 0; e < 4; ++e) {
                const int r = bm + wr * 64 + mi * 16 + g * 4 + e;
                if (REMAP) {
                    const int gr = (r < S_TXT) ? (S_IMG + r) : (r - S_TXT);
                    C[(size_t)gr * DIMC + cl] = acc[mi][ni][e] + bv;
                } else {
                    C[(size_t)r * ldc + cl] = acc[mi][ni][e] + bv;
                }
            }
        }
}

// ---------------------------------------------------------------------------
// LayerNorm + RoPE; Q is pre-scaled by scale*log2(e). fp16 out [NH][S][128].
// ---------------------------------------------------------------------------
__global__ __launch_bounds__(256) void ln_rope_split(
    const float* __restrict__ qkv,
    const float* __restrict__ cost, const float* __restrict__ sint,
    _Float16* __restrict__ Qh, _Float16* __restrict__ Kh)
{
    const int wave = threadIdx.x >> 6;
    const int lane = threadIdx.x & 63;
    const int task = blockIdx.x * 4 + wave;
    const int s = task / 48;
    const int rem = task % 48;
    const int qk = rem / 24;
    const int h = rem % 24;

    const float* p = qkv + (size_t)s * QKV_N + qk * DIMC + h * HD;
    float2 x = *(const float2*)(p + lane * 2);

    float sum = x.x + x.y;
    float sq = x.x * x.x + x.y * x.y;
#pragma unroll
    for (int off = 1; off < 64; off <<= 1) {
        sum += __shfl_xor(sum, off, 64);
        sq  += __shfl_xor(sq, off, 64);
    }
    const float mu = sum * (1.0f / 128.0f);
    const float var = sq * (1.0f / 128.0f) - mu * mu;
    const float rstd = rsqrtf(var + 1e-5f);
    float y0 = (x.x - mu) * rstd;
    float y1 = (x.y - mu) * rstd;

    if (s >= S_TXT) {
        const int ip = s - S_TXT;
        const float c = cost[ip * 64 + lane];
        const float sn = sint[ip * 64 + lane];
        const float o0 = y0 * c - y1 * sn;
        const float o1 = y1 * c + y0 * sn;
        y0 = o0; y1 = o1;
    }
    if (qk == 0) { y0 *= QSCALE; y1 *= QSCALE; }

    const size_t off = ((size_t)h * S_TOT + s) * HD + lane * 2;
    f16x2 hv; hv.x = (_Float16)y0; hv.y = (_Float16)y1;
    *(f16x2*)((qk ? Kh : Qh) + off) = hv;
}

// ---------------------------------------------------------------------------
// V: qkv[s][2*3072 + h*128 + d] -> transposed fp16 Vt [NH][128][S]
// ---------------------------------------------------------------------------
__global__ __launch_bounds__(256) void v_split_transpose(
    const float* __restrict__ qkv, _Float16* __restrict__ Vth)
{
    __shared__ float T[64][132];
    const int h = blockIdx.y;
    const int s0 = blockIdx.x * 64;
    const int t = threadIdx.x;
    {
        const int sl = t >> 2, dp = (t & 3) * 32;
#pragma unroll
        for (int j = 0; j < 8; ++j) {
            float4 v = *(const float4*)(qkv + (size_t)(s0 + sl) * QKV_N + 2 * DIMC + h * HD + dp + j * 4);
            *(float4*)&T[sl][dp + j * 4] = v;
        }
    }
    __syncthreads();
    const int d = t >> 1, sh = (t & 1) * 32;
    f16x8 hv[4];
#pragma unroll
    for (int ss = 0; ss < 32; ++ss)
        hv[ss >> 3][ss & 7] = (_Float16)T[sh + ss][d];
    _Float16* bh = Vth + ((size_t)h * HD + d) * S_TOT + s0 + sh;
#pragma unroll
    for (int j = 0; j < 4; ++j)
        *(f16x8*)(bh + j * 8) = hv[j];
}

// ---------------------------------------------------------------------------
// Flash attention, fp16 MFMA, log2-domain softmax, defer-max (THR=11).
// Block = (64 q, head), 4 waves x 16 q. KVBLK=64. Swapped scores K@Q^T.
// XOR-granule-swizzled LDS (conflict-free reads+stage writes), 40KB LDS.
// 1-D grid, XCD-chunked: each XCD owns 3 whole heads (K/V fits its L2).
// ---------------------------------------------------------------------------
__global__ __launch_bounds__(256) void attn_mfma(
    const _Float16* __restrict__ Qg, const _Float16* __restrict__ Kg,
    const _Float16* __restrict__ Vg, _Float16* __restrict__ aoh)
{
    // Ksh: [db 0..3][kv 0..63][32 d-halfwords], granule slot = dg ^ ((kv>>1)&3) ^ db
    // Vsh: [d 0..127][64 kv-halfwords],         granule slot = kg ^ (d&7)
    // Pah: per-wave [q 0..15][64 kv-halfwords], granule slot = kg ^ (q&7)
    __shared__ __attribute__((aligned(16))) _Float16 Ksh[4 * 64 * 32]; // 16 KB
    __shared__ __attribute__((aligned(16))) _Float16 Vsh[128 * 64];    // 16 KB
    __shared__ __attribute__((aligned(16))) _Float16 Pah[4 * 16 * 64]; //  8 KB

    const int wgid = ((int)blockIdx.x & 7) * 108 + ((int)blockIdx.x >> 3);
    const int h = wgid / 36;
    const int q0 = (wgid % 36) * 64;
    const int tid = threadIdx.x;
    const int w = tid >> 6, l = tid & 63;
    const int lr = l & 15, g = l >> 4;

    // Q fragments (pre-scaled by QSCALE in ln_rope_split)
    const int qrow = q0 + w * 16 + lr;
    const _Float16* qb = Qg + ((size_t)h * S_TOT + qrow) * HD + g * 8;
    f16x8 qh[4];
#pragma unroll
    for (int db = 0; db < 4; ++db)
        qh[db] = *(const f16x8*)(qb + db * 32);

    f32x4 o[8] = {};
    float mrow = -3.0e38f, lrow = 0.0f;

    // swizzled read offsets
    const int kxr = (lr >> 1) & 3;      // K row-XOR component
    const int px  = lr & 7;             // V/P row-XOR component
    int ksl[4];                         // K slot per db (granule*8)
#pragma unroll
    for (int db = 0; db < 4; ++db) ksl[db] = (g ^ kxr ^ db) * 8;
    const int vs0 = (g ^ px) * 8;
    const int vs1 = ((4 + g) ^ px) * 8;

    // staging: K: thread -> kv=tid>>2, d-blk=tid&3 ; V: d=tid>>1, kv-half
    const int kkv = tid >> 2, kdb = tid & 3;
    const int vd = tid >> 1;
    const int kx = (kkv >> 1) & 3;
    const int kbase = kdb * 2048 + kkv * 32;
    const int vbase = vd * 64;
    const int vx = vd & 7;
    const int vg0 = (tid & 1) * 4;
    const _Float16* gK = Kg + ((size_t)h * S_TOT + kkv) * HD + kdb * 32;
    const _Float16* gV = Vg + ((size_t)h * HD + vd) * S_TOT + (tid & 1) * 32;

    uint4 rK0, rK1, rK2, rK3, rV0, rV1, rV2, rV3;
#define LOADKV(kv0) { \
    rK0 = *(const uint4*)(gK + (size_t)(kv0) * HD);      rK1 = *(const uint4*)(gK + (size_t)(kv0) * HD + 8); \
    rK2 = *(const uint4*)(gK + (size_t)(kv0) * HD + 16); rK3 = *(const uint4*)(gK + (size_t)(kv0) * HD + 24); \
    rV0 = *(const uint4*)(gV + (kv0));      rV1 = *(const uint4*)(gV + (kv0) + 8); \
    rV2 = *(const uint4*)(gV + (kv0) + 16); rV3 = *(const uint4*)(gV + (kv0) + 24); }

    LOADKV(0);

    for (int kb = 0; kb < S_TOT / 64; ++kb) {
        __syncthreads();
        *(uint4*)&Ksh[kbase + ((0 ^ kx ^ kdb) * 8)] = rK0;
        *(uint4*)&Ksh[kbase + ((1 ^ kx ^ kdb) * 8)] = rK1;
        *(uint4*)&Ksh[kbase + ((2 ^ kx ^ kdb) * 8)] = rK2;
        *(uint4*)&Ksh[kbase + ((3 ^ kx ^ kdb) * 8)] = rK3;
        *(uint4*)&Vsh[vbase + (((vg0 + 0) ^ vx) * 8)] = rV0;
        *(uint4*)&Vsh[vbase + (((vg0 + 1) ^ vx) * 8)] = rV1;
        *(uint4*)&Vsh[vbase + (((vg0 + 2) ^ vx) * 8)] = rV2;
        *(uint4*)&Vsh[vbase + (((vg0 + 3) ^ vx) * 8)] = rV3;
        __syncthreads();
        if (kb + 1 < S_TOT / 64) LOADKV((kb + 1) * 64);

        // scores S^T: 4 frags (16 kv x 16 q), log2 domain
        f32x4 sT[4] = {};
        __builtin_amdgcn_s_setprio(1);
#pragma unroll
        for (int db = 0; db < 4; ++db)
#pragma unroll
            for (int mf = 0; mf < 4; ++mf) {
                f16x8 kf = *(const f16x8*)&Ksh[db * 2048 + (mf * 16 + lr) * 32 + ksl[db]];
                sT[mf] = MFMA(kf, qh[db], sT[mf]);
            }
        __builtin_amdgcn_s_setprio(0);

        // per-lane max over this tile's 16 kv values (q = lr)
        float pm = -3.0e38f;
#pragma unroll
        for (int mf = 0; mf < 4; ++mf)
#pragma unroll
            for (int e = 0; e < 4; ++e)
                pm = fmaxf(pm, sT[mf][e]);
        pm = fmaxf(pm, __shfl_xor(pm, 16, 64));
        pm = fmaxf(pm, __shfl_xor(pm, 32, 64));

        // defer-max: rescale only when max grew by > 11 (log2 domain)
        if (__any(pm > mrow + 11.0f)) {
            const float mnew = fmaxf(mrow, pm);
            const float alpha = exp2f(mrow - mnew);
            lrow *= alpha;
            mrow = mnew;
            const float a0 = __shfl(alpha, g * 4 + 0, 64);
            const float a1 = __shfl(alpha, g * 4 + 1, 64);
            const float a2 = __shfl(alpha, g * 4 + 2, 64);
            const float a3 = __shfl(alpha, g * 4 + 3, 64);
#pragma unroll
            for (int df = 0; df < 8; ++df) {
                o[df][0] *= a0; o[df][1] *= a1; o[df][2] *= a2; o[df][3] *= a3;
            }
        }

        float rs = 0.0f;
        float ex_[4][4];
#pragma unroll
        for (int mf = 0; mf < 4; ++mf)
#pragma unroll
            for (int e = 0; e < 4; ++e) {
                const float pv = exp2f(sT[mf][e] - mrow);
                ex_[mf][e] = pv;
                rs += pv;
            }
        rs += __shfl_xor(rs, 16, 64);
        rs += __shfl_xor(rs, 32, 64);
        lrow += rs;

        // publish P into per-wave swizzled LDS slice (granule ^ (q&7))
        {
            const int pbase = w * 1024 + lr * 64;
#pragma unroll
            for (int mf = 0; mf < 4; ++mf) {
                const int slot = ((mf * 2 + (g >> 1)) ^ px) * 8 + (g & 1) * 4;
                f16x2 t0; t0.x = (_Float16)ex_[mf][0]; t0.y = (_Float16)ex_[mf][1];
                f16x2 t1; t1.x = (_Float16)ex_[mf][2]; t1.y = (_Float16)ex_[mf][3];
                *(f16x2*)&Pah[pbase + slot]     = t0;
                *(f16x2*)&Pah[pbase + slot + 2] = t1;
            }
        }

        // PV: O(16q x 128d) += P(16x64) @ V(64x128)
        f16x8 pa0 = *(const f16x8*)&Pah[w * 1024 + lr * 64 + vs0];
        f16x8 pa1 = *(const f16x8*)&Pah[w * 1024 + lr * 64 + vs1];
        __builtin_amdgcn_s_setprio(1);
#pragma unroll
        for (int df = 0; df < 8; ++df) {
            f16x8 vf0 = *(const f16x8*)&Vsh[(df * 16 + lr) * 64 + vs0];
            f16x8 vf1 = *(const f16x8*)&Vsh[(df * 16 + lr) * 64 + vs1];
            o[df] = MFMA(pa0, vf0, o[df]);
            o[df] = MFMA(pa1, vf1, o[df]);
        }
        __builtin_amdgcn_s_setprio(0);
    }
#undef LOADKV

    const float inv = 1.0f / lrow;
    const float b0 = __shfl(inv, g * 4 + 0, 64);
    const float b1 = __shfl(inv, g * 4 + 1, 64);
    const float b2 = __shfl(inv, g * 4 + 2, 64);
    const float b3 = __shfl(inv, g * 4 + 3, 64);
    const float bb[4] = {b0, b1, b2, b3};
#pragma unroll
    for (int df = 0; df < 8; ++df)
#pragma unroll
        for (int e = 0; e < 4; ++e) {
            const int r = q0 + w * 16 + g * 4 + e;
            aoh[(size_t)r * DIMC + h * HD + df * 16 + lr] = (_Float16)(o[df][e] * bb[e]);
        }
}

// ---------------------------------------------------------------------------
extern "C" void kernel_launch(void* const* d_in, const int* in_sizes, int n_in,
                              void* d_out, int out_size, void* d_ws, size_t ws_size,
                              hipStream_t stream)
{
    const float* hid  = (const float*)d_in[0];
    const float* enc  = (const float*)d_in[1];
    const float* cost = (const float*)d_in[2];
    const float* sint = (const float*)d_in[3];
    const float* Wqkv = (const float*)d_in[4];
    const float* bqkv = (const float*)d_in[5];
    const float* Wout = (const float*)d_in[6];
    const float* bout = (const float*)d_in[7];
    float* out = (float*)d_out;

    char* ws = (char*)d_ws;
    float*    qkv  = (float*)(ws + 0);            // 84.93 MB; dead after v_transpose
    _Float16* aoh  = (_Float16*)(ws + 0);         // attn out, over qkv
    _Float16* xh   = (_Float16*)(ws + 84934656);  // then Qh over it
    _Float16* Qh   = (_Float16*)(ws + 84934656);
    _Float16* Kh   = (_Float16*)(ws + 99090432);
    _Float16* Wth  = (_Float16*)(ws + 113246208); // full Wqkv^T hi, 56.6 MB (dead after gemm)
    _Float16* Vth  = (_Float16*)(ws + 113246208); // over Wth
    _Float16* W2h  = (_Float16*)(ws + 132120576); // 18.87 MB (after Wth dead)

    split_x<<<S_TOT, 256, 0, stream>>>(enc, hid, xh);
    transpose_w_hi<<<dim3(144, 48), 256, 0, stream>>>(Wqkv, QKV_N, Wth);
    gemm_f16_lds<0><<<18 * 72, 256, 0, stream>>>(xh, Wth, bqkv, qkv, 18, QKV_N);
    transpose_w_hi<<<dim3(48, 48), 256, 0, stream>>>(Wout, DIMC, W2h);
    ln_rope_split<<<(S_TOT * 48) / 4, 256, 0, stream>>>(qkv, cost, sint, Qh, Kh);
    v_split_transpose<<<dim3(36, 24), 256, 0, stream>>>(qkv, Vth);
    attn_mfma<<<864, 256, 0, stream>>>(Qh, Kh, Vth, aoh);
    gemm_f16_lds<1><<<18 * 24, 256, 0, stream>>>(aoh, W2h, bout, out, 18, DIMC);
}